// Round 1
// baseline (2597.433 us; speedup 1.0000x reference)
//
#include <hip/hip_runtime.h>
#include <hip/hip_bf16.h>
#include <math.h>

// ---------------- conv(3->32,k5,p2) + relu + maxpool2 fused ----------------
// One thread computes 4 output channels at one pooled position (window reuse).
__global__ __launch_bounds__(256) void conv_pool_kernel(
    const float* __restrict__ pic, const float* __restrict__ cw,
    const float* __restrict__ cb, float* __restrict__ pooled) {
  __shared__ float ws[2400];  // 32*3*5*5
  for (int i = threadIdx.x; i < 2400; i += 256) ws[i] = cw[i];
  __syncthreads();
  int idx = blockIdx.x * 256 + threadIdx.x;  // ((b*8+ocg)*128+ph)*128+pw
  int pw = idx & 127, ph = (idx >> 7) & 127, ocg = (idx >> 14) & 7, b = idx >> 17;
  const float* pb = pic + (size_t)b * 3 * 65536;
  int h0 = ph * 2 - 2, w0 = pw * 2 - 2;
  float c[4][4];
#pragma unroll
  for (int o = 0; o < 4; ++o)
#pragma unroll
    for (int q = 0; q < 4; ++q) c[o][q] = 0.f;
#pragma unroll
  for (int ic = 0; ic < 3; ++ic) {
    float win[6][6];
#pragma unroll
    for (int r = 0; r < 6; ++r) {
      int h = h0 + r;
      bool hok = (h >= 0) && (h < 256);
#pragma unroll
      for (int cc = 0; cc < 6; ++cc) {
        int w = w0 + cc;
        win[r][cc] = (hok && w >= 0 && w < 256) ? pb[ic * 65536 + h * 256 + w] : 0.f;
      }
    }
#pragma unroll
    for (int o = 0; o < 4; ++o) {
      const float* wk = &ws[((ocg * 4 + o) * 3 + ic) * 25];
#pragma unroll
      for (int kh = 0; kh < 5; ++kh)
#pragma unroll
        for (int kw = 0; kw < 5; ++kw) {
          float wv = wk[kh * 5 + kw];
          c[o][0] += win[kh][kw] * wv;
          c[o][1] += win[kh][kw + 1] * wv;
          c[o][2] += win[kh + 1][kw] * wv;
          c[o][3] += win[kh + 1][kw + 1] * wv;
        }
    }
  }
#pragma unroll
  for (int o = 0; o < 4; ++o) {
    float m = fmaxf(fmaxf(c[o][0], c[o][1]), fmaxf(c[o][2], c[o][3]));
    m = fmaxf(m + cb[ocg * 4 + o], 0.f);
    pooled[(((size_t)b * 32 + ocg * 4 + o) * 128 + ph) * 128 + pw] = m;
  }
}

// ---------------- split-K GEMM: X[32,K] @ W[K,N] -> partial[split][32][N] ----
__global__ __launch_bounds__(256) void gemm32_kernel(
    const float* __restrict__ X, const float* __restrict__ W,
    float* __restrict__ partial, int K, int N, int chunk) {
  __shared__ float xs[32][128];
  int col = blockIdx.x * 256 + threadIdx.x;
  int split = blockIdx.y;
  int k0 = split * chunk;
  int k1 = min(k0 + chunk, K);
  float acc[32];
#pragma unroll
  for (int b = 0; b < 32; ++b) acc[b] = 0.f;
  for (int kt = k0; kt < k1; kt += 128) {
    int kw = min(128, k1 - kt);
    if (kw == 128) {
      for (int i = threadIdx.x; i < 4096; i += 256) {
        int b = i >> 7, kk = i & 127;
        xs[b][kk] = X[(size_t)b * K + kt + kk];
      }
    } else {
      for (int i = threadIdx.x; i < 32 * kw; i += 256) {
        int b = i / kw, kk = i % kw;
        xs[b][kk] = X[(size_t)b * K + kt + kk];
      }
    }
    __syncthreads();
    if (col < N) {
      for (int kk = 0; kk < kw; ++kk) {
        float wv = W[(size_t)(kt + kk) * N + col];
#pragma unroll
        for (int b = 0; b < 32; ++b) acc[b] += xs[b][kk] * wv;
      }
    }
    __syncthreads();
  }
  if (col < N) {
    float* p = partial + (size_t)split * 32 * N + col;
#pragma unroll
    for (int b = 0; b < 32; ++b) p[(size_t)b * N] = acc[b];
  }
}

__global__ __launch_bounds__(256) void reduce_kernel(
    const float* __restrict__ partial, const float* __restrict__ bias,
    float* __restrict__ out, int N, int nsplit, int relu) {
  int i = blockIdx.x * 256 + threadIdx.x;
  if (i >= 32 * N) return;
  int b = i / N, col = i - b * N;
  float s = bias[col];
  for (int sp = 0; sp < nsplit; ++sp) s += partial[((size_t)sp * 32 + b) * N + col];
  out[i] = relu ? fmaxf(s, 0.f) : s;
}

// ---------------- x[32,K] @ W[K,36] + b (optional row softmax) --------------
template <bool SOFTMAX>
__global__ __launch_bounds__(256) void lin36_kernel(
    const float* __restrict__ X, const float* __restrict__ W,
    const float* __restrict__ bias, float* __restrict__ out, int K) {
  __shared__ float xs[4000];
  __shared__ float red[7][36];
  __shared__ float vals[36];
  __shared__ float mx, sm;
  int b = blockIdx.x, tid = threadIdx.x;
  for (int i = tid; i < K; i += 256) xs[i] = X[(size_t)b * K + i];
  __syncthreads();
  if (tid < 252) {
    int col = tid % 36, g = tid / 36;
    float s = 0.f;
    for (int k = g; k < K; k += 7) s += xs[k] * W[(size_t)k * 36 + col];
    red[g][col] = s;
  }
  __syncthreads();
  if (tid < 36) {
    float s = bias[tid];
    for (int g = 0; g < 7; ++g) s += red[g][tid];
    vals[tid] = s;
  }
  __syncthreads();
  if (SOFTMAX) {
    if (tid == 0) {
      float m = -1e30f;
      for (int j = 0; j < 36; ++j) m = fmaxf(m, vals[j]);
      float e = 0.f;
      for (int j = 0; j < 36; ++j) e += expf(vals[j] - m);
      mx = m; sm = e;
    }
    __syncthreads();
    if (tid < 36) out[b * 36 + tid] = expf(vals[tid] - mx) / sm;
  } else {
    if (tid < 36) out[b * 36 + tid] = vals[tid];
  }
}

// ---------------- Wc = gcn_w[75,288] @ gcn_w2[288,72] ----------------------
__global__ __launch_bounds__(256) void wc_kernel(
    const float* __restrict__ w1, const float* __restrict__ w2, float* __restrict__ wc) {
  int i = blockIdx.x * 256 + threadIdx.x;
  if (i >= 75 * 72) return;
  int r = i / 72, c = i - r * 72;
  float s = 0.f;
  for (int k = 0; k < 288; ++k) s += w1[r * 288 + k] * w2[k * 72 + c];
  wc[i] = s;
}

// ---------------- per-drug GCN: max(relu(Hn@(Hn@(X@Wc)))) ------------------
__global__ __launch_bounds__(256) void gcn_kernel(
    const float* __restrict__ Xg, const float* __restrict__ Ag,
    const float* __restrict__ Wc, float* __restrict__ drugfea) {
  __shared__ float Hn[64][64];
  __shared__ float Xs[64][75];
  __shared__ float Wcs[75][72];
  __shared__ float Ys[64][72];
  __shared__ float Ts[64][72];
  int d = blockIdx.x, tid = threadIdx.x;
  const float* Ad = Ag + (size_t)d * 4096;
  const float* Xd = Xg + (size_t)d * 4800;
  for (int i = tid; i < 4096; i += 256) {
    int r = i >> 6, c = i & 63;
    Hn[r][c] = (r == c) ? 1.f : Ad[c * 64 + r];  // A^T, diag forced to 1
  }
  for (int i = tid; i < 4800; i += 256) Xs[i / 75][i % 75] = Xd[i];
  for (int i = tid; i < 5400; i += 256) Wcs[i / 72][i % 72] = Wc[i];
  __syncthreads();
  if (tid < 64) {
    float s = 0.f;
    for (int c = 0; c < 64; ++c) s += Hn[tid][c];
    float inv = (s == 0.f) ? 0.f : 1.f / s;
    for (int c = 0; c < 64; ++c) Hn[tid][c] *= inv;
  }
  __syncthreads();
  for (int t = tid; t < 4608; t += 256) {
    int i = t / 72, j = t - (t / 72) * 72;
    float s = 0.f;
    for (int k = 0; k < 75; ++k) s += Xs[i][k] * Wcs[k][j];
    Ys[i][j] = s;
  }
  __syncthreads();
  for (int t = tid; t < 4608; t += 256) {
    int i = t / 72, j = t - (t / 72) * 72;
    float s = 0.f;
    for (int k = 0; k < 64; ++k) s += Hn[i][k] * Ys[k][j];
    Ts[i][j] = s;
  }
  __syncthreads();
  for (int t = tid; t < 4608; t += 256) {
    int i = t / 72, j = t - (t / 72) * 72;
    float s = 0.f;
    for (int k = 0; k < 64; ++k) s += Hn[i][k] * Ts[k][j];
    Ys[i][j] = fmaxf(s, 0.f);  // reuse Ys as relu(out)
  }
  __syncthreads();
  if (tid < 72) {
    float m = Ys[0][tid];
    for (int i = 1; i < 64; ++i) m = fmaxf(m, Ys[i][tid]);
    drugfea[d * 72 + tid] = m;
  }
}

// ---------------- attention + CLIP loss + cell_cat (single block) ----------
__global__ __launch_bounds__(256) void head_kernel(
    const float* __restrict__ rna1, const float* __restrict__ cnv1,
    const float* __restrict__ pic1r, const float* __restrict__ aw1,
    const float* __restrict__ ab1, const float* __restrict__ aw2,
    const float* __restrict__ scale_p, float* __restrict__ cell_cat,
    float* __restrict__ dout) {
  __shared__ float z[2][32][36];
  __shared__ float pic1n[32][36];
  __shared__ float celln[32][36];
  __shared__ float fea[32][32];
  __shared__ float wvp[64];
  __shared__ float beta0, beta1;
  __shared__ float rowl[32], coll[32];
  int tid = threadIdx.x;
  for (int i = tid; i < 1152; i += 256) {
    int b = i / 36, k = i - (i / 36) * 36;
    z[0][b][k] = rna1[i];
    z[1][b][k] = cnv1[i];
    pic1n[b][k] = pic1r[i];
  }
  __syncthreads();
  {  // attention scores: 64 (b,v) pairs x 4 threads over h
    int p = tid >> 2, sub = tid & 3;
    int b = p >> 1, v = p & 1;
    float s = 0.f;
    for (int h = sub; h < 128; h += 4) {
      float a = ab1[h];
      for (int k = 0; k < 36; ++k) a += z[v][b][k] * aw1[k * 128 + h];
      s += tanhf(a) * aw2[h];
    }
    s += __shfl_down(s, 1, 64);
    s += __shfl_down(s, 2, 64);
    if (sub == 0) wvp[p] = s;
  }
  __syncthreads();
  if (tid == 0) {
    float w0 = 0.f, w1 = 0.f;
    for (int b = 0; b < 32; ++b) { w0 += wvp[b * 2]; w1 += wvp[b * 2 + 1]; }
    w0 /= 32.f; w1 /= 32.f;
    float m = fmaxf(w0, w1);
    float e0 = expf(w0 - m), e1 = expf(w1 - m);
    beta0 = e0 / (e0 + e1); beta1 = e1 / (e0 + e1);
  }
  __syncthreads();
  for (int i = tid; i < 1152; i += 256) {
    int b = i / 36, k = i - (i / 36) * 36;
    celln[b][k] = beta0 * z[0][b][k] + beta1 * z[1][b][k];
  }
  __syncthreads();
  if (tid < 32) {  // normalize pic1 rows
    float s = 0.f;
    for (int k = 0; k < 36; ++k) { float x = pic1n[tid][k]; s += x * x; }
    float inv = 1.f / sqrtf(s);
    for (int k = 0; k < 36; ++k) pic1n[tid][k] *= inv;
  } else if (tid < 64) {  // normalize cell rows
    int b = tid - 32;
    float s = 0.f;
    for (int k = 0; k < 36; ++k) { float x = celln[b][k]; s += x * x; }
    float inv = 1.f / sqrtf(s);
    for (int k = 0; k < 36; ++k) celln[b][k] *= inv;
  }
  __syncthreads();
  for (int i = tid; i < 1152; i += 256) {  // cell_cat = [cell, pic1]
    int b = i / 36, k = i - (i / 36) * 36;
    cell_cat[b * 72 + k] = celln[b][k];
    cell_cat[b * 72 + 36 + k] = pic1n[b][k];
  }
  float sc = *scale_p;
  for (int t = tid; t < 1024; t += 256) {
    int i = t >> 5, j = t & 31;
    float s = 0.f;
    for (int k = 0; k < 36; ++k) s += pic1n[i][k] * celln[j][k];
    fea[i][j] = sc * s;
  }
  __syncthreads();
  if (tid < 32) {
    float m = -1e30f;
    for (int j = 0; j < 32; ++j) m = fmaxf(m, fea[tid][j]);
    float e = 0.f;
    for (int j = 0; j < 32; ++j) e += expf(fea[tid][j] - m);
    rowl[tid] = (logf(e) + m) - fea[tid][tid];
  } else if (tid < 64) {
    int j = tid - 32;
    float m = -1e30f;
    for (int i = 0; i < 32; ++i) m = fmaxf(m, fea[i][j]);
    float e = 0.f;
    for (int i = 0; i < 32; ++i) e += expf(fea[i][j] - m);
    coll[j] = (logf(e) + m) - fea[j][j];
  }
  __syncthreads();
  if (tid == 0) {
    float s1 = 0.f, s2 = 0.f;
    for (int i = 0; i < 32; ++i) { s1 += rowl[i]; s2 += coll[i]; }
    dout[1] = 0.5f * (s1 / 32.f + s2 / 32.f);  // total_loss2
  }
}

// ---------------- pair head + per-block CE partial sums --------------------
__global__ __launch_bounds__(256) void pair_kernel(
    const float* __restrict__ cell_cat, const float* __restrict__ drugfea,
    const int* __restrict__ idx, const int* __restrict__ target,
    const float* __restrict__ w1, const float* __restrict__ b1,
    const float* __restrict__ w2, const float* __restrict__ b2,
    float* __restrict__ bp_out, float* __restrict__ tgt_out,
    float* __restrict__ blocksums) {
  __shared__ float w1s[144][36];
  __shared__ float ccs[32][72];
  __shared__ float dfs[128][72];
  __shared__ float lsum[256];
  int tid = threadIdx.x;
  for (int i = tid; i < 144 * 36; i += 256) w1s[i / 36][i - (i / 36) * 36] = w1[i];
  for (int i = tid; i < 2304; i += 256) ccs[i / 72][i - (i / 72) * 72] = cell_cat[i];
  for (int i = tid; i < 9216; i += 256) dfs[i / 72][i - (i / 72) * 72] = drugfea[i];
  __syncthreads();
  int p = blockIdx.x * 256 + tid;
  int ci = idx[p * 2], dj = idx[p * 2 + 1];
  float h[36];
#pragma unroll
  for (int j = 0; j < 36; ++j) h[j] = b1[j];
  for (int k = 0; k < 72; ++k) {
    float x = ccs[ci][k];
#pragma unroll
    for (int j = 0; j < 36; ++j) h[j] += x * w1s[k][j];
  }
  for (int k = 0; k < 72; ++k) {
    float x = dfs[dj][k];
#pragma unroll
    for (int j = 0; j < 36; ++j) h[j] += x * w1s[72 + k][j];
  }
  float l0 = b2[0], l1 = b2[1];
#pragma unroll
  for (int j = 0; j < 36; ++j) {
    float hv = fmaxf(h[j], 0.f);
    l0 += hv * w2[j * 2];
    l1 += hv * w2[j * 2 + 1];
  }
  float m = fmaxf(l0, l1);
  float e0 = expf(l0 - m), e1 = expf(l1 - m);
  float inv = 1.f / (e0 + e1);
  float p0 = e0 * inv, p1 = e1 * inv;
  bp_out[p * 2] = p0;
  bp_out[p * 2 + 1] = p1;
  // reference applies log_softmax to the softmax probs
  int t = target[p];
  float mm = fmaxf(p0, p1);
  float lse = logf(expf(p0 - mm) + expf(p1 - mm)) + mm;
  float chosen = t ? p1 : p0;
  lsum[tid] = lse - chosen;
  tgt_out[p] = (float)t;
  __syncthreads();
  for (int s = 128; s > 0; s >>= 1) {
    if (tid < s) lsum[tid] += lsum[tid + s];
    __syncthreads();
  }
  if (tid == 0) blocksums[blockIdx.x] = lsum[0];
}

__global__ void final_kernel(const float* __restrict__ blocksums, float* __restrict__ dout) {
  if (threadIdx.x == 0 && blockIdx.x == 0) {
    float s = 0.f;
    for (int i = 0; i < 16; ++i) s += blocksums[i];
    dout[0] = s / 4096.f;  // loss1
  }
}

extern "C" void kernel_launch(void* const* d_in, const int* in_sizes, int n_in,
                              void* d_out, int out_size, void* d_ws, size_t ws_size,
                              hipStream_t stream) {
  (void)in_sizes; (void)n_in; (void)out_size; (void)ws_size;
  const float* pic        = (const float*)d_in[0];
  const float* rna        = (const float*)d_in[1];
  const float* cnv        = (const float*)d_in[2];
  const float* drug_fea   = (const float*)d_in[3];
  const float* drug_adj   = (const float*)d_in[4];
  const int*   index_list = (const int*)d_in[5];
  const int*   target     = (const int*)d_in[6];
  const float* logit_scale= (const float*)d_in[7];
  const float* conv_w     = (const float*)d_in[8];
  const float* conv_b     = (const float*)d_in[9];
  const float* fc1_w      = (const float*)d_in[10];
  const float* fc1_b      = (const float*)d_in[11];
  const float* fc2_w      = (const float*)d_in[12];
  const float* fc2_b      = (const float*)d_in[13];
  const float* m1w1       = (const float*)d_in[14];
  const float* m1b1       = (const float*)d_in[15];
  const float* m1w2       = (const float*)d_in[16];
  const float* m1b2       = (const float*)d_in[17];
  const float* m2w1       = (const float*)d_in[18];
  const float* m2b1       = (const float*)d_in[19];
  const float* m2w2       = (const float*)d_in[20];
  const float* m2b2       = (const float*)d_in[21];
  const float* aw1        = (const float*)d_in[22];
  const float* ab1        = (const float*)d_in[23];
  const float* aw2        = (const float*)d_in[24];
  const float* ew1        = (const float*)d_in[25];
  const float* eb1        = (const float*)d_in[26];
  const float* ew2        = (const float*)d_in[27];
  const float* eb2        = (const float*)d_in[28];
  const float* gw         = (const float*)d_in[29];
  const float* gw2        = (const float*)d_in[30];

  float* ws = (float*)d_ws;
  float* pooled  = ws;                   // 16,777,216 f
  float* partial = ws + 16777216;        //  8,388,608 f
  float* fcact   = ws + 25165824;        //     32,768 f
  float* h1      = ws + 25198592;        //    128,000 f
  float* h2      = ws + 25326592;        //    128,000 f
  float* rna1    = ws + 25454592;        //      1,152 f
  float* cnv1    = ws + 25455744;
  float* pic1r   = ws + 25456896;
  float* wcb     = ws + 25458048;        //      5,400 f
  float* drugf   = ws + 25463448;        //      9,216 f
  float* cellcat = ws + 25472664;        //      2,304 f
  float* bsums   = ws + 25474968;        //         16 f

  float* out = (float*)d_out;

  // image branch
  conv_pool_kernel<<<16384, 256, 0, stream>>>(pic, conv_w, conv_b, pooled);
  {
    dim3 g(4, 256);
    gemm32_kernel<<<g, 256, 0, stream>>>(pooled, fc1_w, partial, 524288, 1024, 2048);
    reduce_kernel<<<128, 256, 0, stream>>>(partial, fc1_b, fcact, 1024, 256, 1);
  }
  // omics branches
  {
    dim3 g(16, 63);
    gemm32_kernel<<<g, 256, 0, stream>>>(rna, m1w1, partial, 16000, 4000, 256);
    reduce_kernel<<<500, 256, 0, stream>>>(partial, m1b1, h1, 4000, 63, 1);
  }
  {
    dim3 g(16, 63);
    gemm32_kernel<<<g, 256, 0, stream>>>(cnv, m2w1, partial, 16000, 4000, 256);
    reduce_kernel<<<500, 256, 0, stream>>>(partial, m2b1, h2, 4000, 63, 1);
  }
  lin36_kernel<true><<<32, 256, 0, stream>>>(h1, m1w2, m1b2, rna1, 4000);
  lin36_kernel<true><<<32, 256, 0, stream>>>(h2, m2w2, m2b2, cnv1, 4000);
  lin36_kernel<false><<<32, 256, 0, stream>>>(fcact, fc2_w, fc2_b, pic1r, 1024);

  // drug GCN
  wc_kernel<<<22, 256, 0, stream>>>(gw, gw2, wcb);
  gcn_kernel<<<128, 256, 0, stream>>>(drug_fea, drug_adj, wcb, drugf);

  // attention + CLIP loss (writes out[1], cellcat)
  head_kernel<<<1, 256, 0, stream>>>(rna1, cnv1, pic1r, aw1, ab1, aw2,
                                     logit_scale, cellcat, out);

  // pair prediction head (writes Bp, target copy, per-block CE sums)
  pair_kernel<<<16, 256, 0, stream>>>(cellcat, drugf, index_list, target,
                                      ew1, eb1, ew2, eb2,
                                      out + 2, out + 2 + 8192, bsums);
  final_kernel<<<1, 64, 0, stream>>>(bsums, out);
}

// Round 3
// 2570.802 us; speedup vs baseline: 1.0104x; 1.0104x over previous
//
#include <hip/hip_runtime.h>
#include <hip/hip_bf16.h>
#include <math.h>

__device__ __forceinline__ void fma4(float4& a, float s, const float4& v) {
  a.x += s * v.x; a.y += s * v.y; a.z += s * v.z; a.w += s * v.w;
}

// ---------------- conv(3->32,k5,p2) + relu + maxpool2 fused ----------------
// grid: 32 b x 2 ocg2 x 64 ph-pairs. block: 256 = 2 ph x 128 pw.
// Each thread: one pooled position, 16 output channels, window from LDS tile.
__global__ __launch_bounds__(256) void conv_pool_kernel(
    const float* __restrict__ pic, const float* __restrict__ cw,
    const float* __restrict__ cb, float* __restrict__ pooled) {
  __shared__ float ws[1200];          // 16 oc * 3 ic * 25
  __shared__ float tile[3][8][260];   // zero-padded input rows
  int bid = blockIdx.x;
  int php = bid & 63, ocg2 = (bid >> 6) & 1, b = bid >> 7;
  int tid = threadIdx.x;
  int pw = tid & 127, phl = tid >> 7;
  int ph = php * 2 + phl;
  for (int i = tid; i < 1200; i += 256) ws[i] = cw[ocg2 * 1200 + i];
  int h_base = php * 4 - 2;
  for (int i = tid; i < 3 * 8 * 260; i += 256) {
    int c = i % 260; int rr = (i / 260) & 7; int ic = i / (260 * 8);
    int h = h_base + rr, w = c - 2;
    float v = 0.f;
    if (h >= 0 && h < 256 && w >= 0 && w < 256)
      v = pic[((size_t)b * 3 + ic) * 65536 + h * 256 + w];
    tile[ic][rr][c] = v;
  }
  __syncthreads();
  float acc[16][4];
#pragma unroll
  for (int o = 0; o < 16; ++o)
#pragma unroll
    for (int q = 0; q < 4; ++q) acc[o][q] = 0.f;
  int r0 = phl * 2;      // local tile row of conv position (h0 - h_base)
  int c0 = pw * 2;       // tile col of w0 (already includes -2 pad shift)
#pragma unroll
  for (int ic = 0; ic < 3; ++ic) {
    float win[6][6];
#pragma unroll
    for (int r = 0; r < 6; ++r)
#pragma unroll
      for (int cc = 0; cc < 6; ++cc) win[r][cc] = tile[ic][r0 + r][c0 + cc];
#pragma unroll
    for (int o = 0; o < 16; ++o) {
      const float* wk = &ws[(o * 3 + ic) * 25];
#pragma unroll
      for (int kh = 0; kh < 5; ++kh)
#pragma unroll
        for (int kw = 0; kw < 5; ++kw) {
          float wv = wk[kh * 5 + kw];
          acc[o][0] += win[kh][kw] * wv;
          acc[o][1] += win[kh][kw + 1] * wv;
          acc[o][2] += win[kh + 1][kw] * wv;
          acc[o][3] += win[kh + 1][kw + 1] * wv;
        }
    }
  }
#pragma unroll
  for (int o = 0; o < 16; ++o) {
    float m = fmaxf(fmaxf(acc[o][0], acc[o][1]), fmaxf(acc[o][2], acc[o][3]));
    m = fmaxf(m + cb[ocg2 * 16 + o], 0.f);
    pooled[(((size_t)b * 32 + ocg2 * 16 + o) * 128 + ph) * 128 + pw] = m;
  }
}

// ------- split-K GEMM: X[32,K] @ W[K,N] -> partial[split][32][N] -----------
// 4 columns per thread (float4 W loads), X tile staged transposed in LDS so
// the inner loop is 8 broadcast ds_read_b128 + 128 FMA per k.
__global__ __launch_bounds__(256) void gemm32v_kernel(
    const float* __restrict__ X, const float* __restrict__ W,
    float* __restrict__ partial, int K, int N, int chunk) {
  __shared__ float xs[128][32];   // [kk][b]
  int tid = threadIdx.x;
  int colv = blockIdx.x * 256 + tid;   // float4 column index
  int col0 = colv * 4;
  bool active = col0 < N;
  int split = blockIdx.y;
  int k0 = split * chunk, k1 = min(k0 + chunk, K);
  int Nv = N >> 2;
  const float4* Wv = (const float4*)W;
  float4 acc[32];
#pragma unroll
  for (int b = 0; b < 32; ++b) acc[b] = make_float4(0.f, 0.f, 0.f, 0.f);
  for (int kt = k0; kt < k1; kt += 128) {
    int kw = min(128, k1 - kt);
    __syncthreads();
    if (kw == 128) {
      for (int i = tid; i < 4096; i += 256) {
        int b = i >> 7, kk = i & 127;
        xs[kk][b] = X[(size_t)b * K + kt + kk];
      }
    } else {
      for (int i = tid; i < 32 * kw; i += 256) {
        int b = i / kw, kk = i - b * kw;
        xs[kk][b] = X[(size_t)b * K + kt + kk];
      }
    }
    __syncthreads();
    if (active) {
      if (kw == 128) {
#pragma unroll 4
        for (int kk = 0; kk < 128; ++kk) {
          float4 w4 = Wv[(size_t)(kt + kk) * Nv + colv];
          const float4* xr = (const float4*)xs[kk];
#pragma unroll
          for (int b4 = 0; b4 < 8; ++b4) {
            float4 xv = xr[b4];
            fma4(acc[b4 * 4 + 0], xv.x, w4);
            fma4(acc[b4 * 4 + 1], xv.y, w4);
            fma4(acc[b4 * 4 + 2], xv.z, w4);
            fma4(acc[b4 * 4 + 3], xv.w, w4);
          }
        }
      } else {
        for (int kk = 0; kk < kw; ++kk) {
          float4 w4 = Wv[(size_t)(kt + kk) * Nv + colv];
          const float4* xr = (const float4*)xs[kk];
#pragma unroll
          for (int b4 = 0; b4 < 8; ++b4) {
            float4 xv = xr[b4];
            fma4(acc[b4 * 4 + 0], xv.x, w4);
            fma4(acc[b4 * 4 + 1], xv.y, w4);
            fma4(acc[b4 * 4 + 2], xv.z, w4);
            fma4(acc[b4 * 4 + 3], xv.w, w4);
          }
        }
      }
    }
  }
  if (active) {
    float* p = partial + (size_t)split * 32 * N + col0;
#pragma unroll
    for (int b = 0; b < 32; ++b) *(float4*)(p + (size_t)b * N) = acc[b];
  }
}

__global__ __launch_bounds__(256) void reduce_kernel(
    const float* __restrict__ partial, const float* __restrict__ bias,
    float* __restrict__ out, int N, int nsplit, int relu) {
  int i = blockIdx.x * 256 + threadIdx.x;
  if (i >= 32 * N) return;
  int b = i / N, col = i - b * N;
  float s = bias[col];
  for (int sp = 0; sp < nsplit; ++sp) s += partial[((size_t)sp * 32 + b) * N + col];
  out[i] = relu ? fmaxf(s, 0.f) : s;
}

// ---------------- x[32,K] @ W[K,36] + b (optional row softmax) --------------
template <bool SOFTMAX>
__global__ __launch_bounds__(256) void lin36_kernel(
    const float* __restrict__ X, const float* __restrict__ W,
    const float* __restrict__ bias, float* __restrict__ out, int K) {
  __shared__ float xs[4000];
  __shared__ float red[7][36];
  __shared__ float vals[36];
  __shared__ float mx, sm;
  int b = blockIdx.x, tid = threadIdx.x;
  for (int i = tid; i < K; i += 256) xs[i] = X[(size_t)b * K + i];
  __syncthreads();
  if (tid < 252) {
    int col = tid % 36, g = tid / 36;
    float s = 0.f;
    for (int k = g; k < K; k += 7) s += xs[k] * W[(size_t)k * 36 + col];
    red[g][col] = s;
  }
  __syncthreads();
  if (tid < 36) {
    float s = bias[tid];
    for (int g = 0; g < 7; ++g) s += red[g][tid];
    vals[tid] = s;
  }
  __syncthreads();
  if (SOFTMAX) {
    if (tid == 0) {
      float m = -1e30f;
      for (int j = 0; j < 36; ++j) m = fmaxf(m, vals[j]);
      float e = 0.f;
      for (int j = 0; j < 36; ++j) e += expf(vals[j] - m);
      mx = m; sm = e;
    }
    __syncthreads();
    if (tid < 36) out[b * 36 + tid] = expf(vals[tid] - mx) / sm;
  } else {
    if (tid < 36) out[b * 36 + tid] = vals[tid];
  }
}

// ---------------- Wc = gcn_w[75,288] @ gcn_w2[288,72] ----------------------
__global__ __launch_bounds__(256) void wc_kernel(
    const float* __restrict__ w1, const float* __restrict__ w2, float* __restrict__ wc) {
  int i = blockIdx.x * 256 + threadIdx.x;
  if (i >= 75 * 72) return;
  int r = i / 72, c = i - r * 72;
  float s = 0.f;
  for (int k = 0; k < 288; ++k) s += w1[r * 288 + k] * w2[k * 72 + c];
  wc[i] = s;
}

// ---------------- per-drug GCN: max(relu(Hn@(Hn@(X@Wc)))) ------------------
__global__ __launch_bounds__(256) void gcn_kernel(
    const float* __restrict__ Xg, const float* __restrict__ Ag,
    const float* __restrict__ Wc, float* __restrict__ drugfea) {
  __shared__ float Hn[64][64];
  __shared__ float Xs[64][75];
  __shared__ float Wcs[75][72];
  __shared__ float Ys[64][72];
  __shared__ float Ts[64][72];
  int d = blockIdx.x, tid = threadIdx.x;
  const float* Ad = Ag + (size_t)d * 4096;
  const float* Xd = Xg + (size_t)d * 4800;
  for (int i = tid; i < 4096; i += 256) {
    int r = i >> 6, c = i & 63;
    Hn[r][c] = (r == c) ? 1.f : Ad[c * 64 + r];  // A^T, diag forced to 1
  }
  for (int i = tid; i < 4800; i += 256) Xs[i / 75][i % 75] = Xd[i];
  for (int i = tid; i < 5400; i += 256) Wcs[i / 72][i % 72] = Wc[i];
  __syncthreads();
  if (tid < 64) {
    float s = 0.f;
    for (int c = 0; c < 64; ++c) s += Hn[tid][c];
    float inv = (s == 0.f) ? 0.f : 1.f / s;
    for (int c = 0; c < 64; ++c) Hn[tid][c] *= inv;
  }
  __syncthreads();
  for (int t = tid; t < 4608; t += 256) {
    int i = t / 72, j = t - (t / 72) * 72;
    float s = 0.f;
    for (int k = 0; k < 75; ++k) s += Xs[i][k] * Wcs[k][j];
    Ys[i][j] = s;
  }
  __syncthreads();
  for (int t = tid; t < 4608; t += 256) {
    int i = t / 72, j = t - (t / 72) * 72;
    float s = 0.f;
    for (int k = 0; k < 64; ++k) s += Hn[i][k] * Ys[k][j];
    Ts[i][j] = s;
  }
  __syncthreads();
  for (int t = tid; t < 4608; t += 256) {
    int i = t / 72, j = t - (t / 72) * 72;
    float s = 0.f;
    for (int k = 0; k < 64; ++k) s += Hn[i][k] * Ts[k][j];
    Ys[i][j] = fmaxf(s, 0.f);
  }
  __syncthreads();
  if (tid < 72) {
    float m = Ys[0][tid];
    for (int i = 1; i < 64; ++i) m = fmaxf(m, Ys[i][tid]);
    drugfea[d * 72 + tid] = m;
  }
}

// ---------------- attention + CLIP loss + cell_cat (single block) ----------
__global__ __launch_bounds__(256) void head_kernel(
    const float* __restrict__ rna1, const float* __restrict__ cnv1,
    const float* __restrict__ pic1r, const float* __restrict__ aw1,
    const float* __restrict__ ab1, const float* __restrict__ aw2,
    const float* __restrict__ scale_p, float* __restrict__ cell_cat,
    float* __restrict__ dout) {
  __shared__ float z[2][32][36];
  __shared__ float pic1n[32][36];
  __shared__ float celln[32][36];
  __shared__ float fea[32][32];
  __shared__ float wvp[64];
  __shared__ float beta0, beta1;
  __shared__ float rowl[32], coll[32];
  int tid = threadIdx.x;
  for (int i = tid; i < 1152; i += 256) {
    int b = i / 36, k = i - (i / 36) * 36;
    z[0][b][k] = rna1[i];
    z[1][b][k] = cnv1[i];
    pic1n[b][k] = pic1r[i];
  }
  __syncthreads();
  {
    int p = tid >> 2, sub = tid & 3;
    int b = p >> 1, v = p & 1;
    float s = 0.f;
    for (int h = sub; h < 128; h += 4) {
      float a = ab1[h];
      for (int k = 0; k < 36; ++k) a += z[v][b][k] * aw1[k * 128 + h];
      s += tanhf(a) * aw2[h];
    }
    s += __shfl_down(s, 1, 64);
    s += __shfl_down(s, 2, 64);
    if (sub == 0) wvp[p] = s;
  }
  __syncthreads();
  if (tid == 0) {
    float w0 = 0.f, w1 = 0.f;
    for (int b = 0; b < 32; ++b) { w0 += wvp[b * 2]; w1 += wvp[b * 2 + 1]; }
    w0 /= 32.f; w1 /= 32.f;
    float m = fmaxf(w0, w1);
    float e0 = expf(w0 - m), e1 = expf(w1 - m);
    beta0 = e0 / (e0 + e1); beta1 = e1 / (e0 + e1);
  }
  __syncthreads();
  for (int i = tid; i < 1152; i += 256) {
    int b = i / 36, k = i - (i / 36) * 36;
    celln[b][k] = beta0 * z[0][b][k] + beta1 * z[1][b][k];
  }
  __syncthreads();
  if (tid < 32) {
    float s = 0.f;
    for (int k = 0; k < 36; ++k) { float x = pic1n[tid][k]; s += x * x; }
    float inv = 1.f / sqrtf(s);
    for (int k = 0; k < 36; ++k) pic1n[tid][k] *= inv;
  } else if (tid < 64) {
    int b = tid - 32;
    float s = 0.f;
    for (int k = 0; k < 36; ++k) { float x = celln[b][k]; s += x * x; }
    float inv = 1.f / sqrtf(s);
    for (int k = 0; k < 36; ++k) celln[b][k] *= inv;
  }
  __syncthreads();
  for (int i = tid; i < 1152; i += 256) {
    int b = i / 36, k = i - (i / 36) * 36;
    cell_cat[b * 72 + k] = celln[b][k];
    cell_cat[b * 72 + 36 + k] = pic1n[b][k];
  }
  float sc = *scale_p;
  for (int t = tid; t < 1024; t += 256) {
    int i = t >> 5, j = t & 31;
    float s = 0.f;
    for (int k = 0; k < 36; ++k) s += pic1n[i][k] * celln[j][k];
    fea[i][j] = sc * s;
  }
  __syncthreads();
  if (tid < 32) {
    float m = -1e30f;
    for (int j = 0; j < 32; ++j) m = fmaxf(m, fea[tid][j]);
    float e = 0.f;
    for (int j = 0; j < 32; ++j) e += expf(fea[tid][j] - m);
    rowl[tid] = (logf(e) + m) - fea[tid][tid];
  } else if (tid < 64) {
    int j = tid - 32;
    float m = -1e30f;
    for (int i = 0; i < 32; ++i) m = fmaxf(m, fea[i][j]);
    float e = 0.f;
    for (int i = 0; i < 32; ++i) e += expf(fea[i][j] - m);
    coll[j] = (logf(e) + m) - fea[j][j];
  }
  __syncthreads();
  if (tid == 0) {
    float s1 = 0.f, s2 = 0.f;
    for (int i = 0; i < 32; ++i) { s1 += rowl[i]; s2 += coll[i]; }
    dout[1] = 0.5f * (s1 / 32.f + s2 / 32.f);
  }
}

// ---------------- pair head + per-block CE partial sums --------------------
__global__ __launch_bounds__(256) void pair_kernel(
    const float* __restrict__ cell_cat, const float* __restrict__ drugfea,
    const int* __restrict__ idx, const int* __restrict__ target,
    const float* __restrict__ w1, const float* __restrict__ b1,
    const float* __restrict__ w2, const float* __restrict__ b2,
    float* __restrict__ bp_out, float* __restrict__ tgt_out,
    float* __restrict__ blocksums) {
  __shared__ float w1s[144][36];
  __shared__ float ccs[32][72];
  __shared__ float dfs[128][72];
  __shared__ float lsum[256];
  int tid = threadIdx.x;
  for (int i = tid; i < 144 * 36; i += 256) w1s[i / 36][i - (i / 36) * 36] = w1[i];
  for (int i = tid; i < 2304; i += 256) ccs[i / 72][i - (i / 72) * 72] = cell_cat[i];
  for (int i = tid; i < 9216; i += 256) dfs[i / 72][i - (i / 72) * 72] = drugfea[i];
  __syncthreads();
  int p = blockIdx.x * 256 + tid;
  int ci = idx[p * 2], dj = idx[p * 2 + 1];
  float h[36];
#pragma unroll
  for (int j = 0; j < 36; ++j) h[j] = b1[j];
  for (int k = 0; k < 72; ++k) {
    float x = ccs[ci][k];
#pragma unroll
    for (int j = 0; j < 36; ++j) h[j] += x * w1s[k][j];
  }
  for (int k = 0; k < 72; ++k) {
    float x = dfs[dj][k];
#pragma unroll
    for (int j = 0; j < 36; ++j) h[j] += x * w1s[72 + k][j];
  }
  float l0 = b2[0], l1 = b2[1];
#pragma unroll
  for (int j = 0; j < 36; ++j) {
    float hv = fmaxf(h[j], 0.f);
    l0 += hv * w2[j * 2];
    l1 += hv * w2[j * 2 + 1];
  }
  float m = fmaxf(l0, l1);
  float e0 = expf(l0 - m), e1 = expf(l1 - m);
  float inv = 1.f / (e0 + e1);
  float p0 = e0 * inv, p1 = e1 * inv;
  bp_out[p * 2] = p0;
  bp_out[p * 2 + 1] = p1;
  int t = target[p];
  float mm = fmaxf(p0, p1);
  float lse = logf(expf(p0 - mm) + expf(p1 - mm)) + mm;
  float chosen = t ? p1 : p0;
  lsum[tid] = lse - chosen;
  tgt_out[p] = (float)t;
  __syncthreads();
  for (int s = 128; s > 0; s >>= 1) {
    if (tid < s) lsum[tid] += lsum[tid + s];
    __syncthreads();
  }
  if (tid == 0) blocksums[blockIdx.x] = lsum[0];
}

__global__ void final_kernel(const float* __restrict__ blocksums, float* __restrict__ dout) {
  if (threadIdx.x == 0 && blockIdx.x == 0) {
    float s = 0.f;
    for (int i = 0; i < 16; ++i) s += blocksums[i];
    dout[0] = s / 4096.f;
  }
}

extern "C" void kernel_launch(void* const* d_in, const int* in_sizes, int n_in,
                              void* d_out, int out_size, void* d_ws, size_t ws_size,
                              hipStream_t stream) {
  (void)in_sizes; (void)n_in; (void)out_size; (void)ws_size;
  const float* pic        = (const float*)d_in[0];
  const float* rna        = (const float*)d_in[1];
  const float* cnv        = (const float*)d_in[2];
  const float* drug_fea   = (const float*)d_in[3];
  const float* drug_adj   = (const float*)d_in[4];
  const int*   index_list = (const int*)d_in[5];
  const int*   target     = (const int*)d_in[6];
  const float* logit_scale= (const float*)d_in[7];
  const float* conv_w     = (const float*)d_in[8];
  const float* conv_b     = (const float*)d_in[9];
  const float* fc1_w      = (const float*)d_in[10];
  const float* fc1_b      = (const float*)d_in[11];
  const float* fc2_w      = (const float*)d_in[12];
  const float* fc2_b      = (const float*)d_in[13];
  const float* m1w1       = (const float*)d_in[14];
  const float* m1b1       = (const float*)d_in[15];
  const float* m1w2       = (const float*)d_in[16];
  const float* m1b2       = (const float*)d_in[17];
  const float* m2w1       = (const float*)d_in[18];
  const float* m2b1       = (const float*)d_in[19];
  const float* m2w2       = (const float*)d_in[20];
  const float* m2b2       = (const float*)d_in[21];
  const float* aw1        = (const float*)d_in[22];
  const float* ab1        = (const float*)d_in[23];
  const float* aw2        = (const float*)d_in[24];
  const float* ew1        = (const float*)d_in[25];
  const float* eb1        = (const float*)d_in[26];
  const float* ew2        = (const float*)d_in[27];
  const float* eb2        = (const float*)d_in[28];
  const float* gw         = (const float*)d_in[29];
  const float* gw2        = (const float*)d_in[30];

  float* ws = (float*)d_ws;
  float* pooled  = ws;                   // 16,777,216 f
  float* partial = ws + 16777216;        // 16,777,216 f (max of fc1/mlp)
  float* fcact   = ws + 33554432;        //     32,768 f
  float* h1      = ws + 33587200;        //    128,000 f
  float* h2      = ws + 33715200;        //    128,000 f
  float* rna1    = ws + 33843200;        //      1,152 f
  float* cnv1    = ws + 33844352;
  float* pic1r   = ws + 33845504;
  float* wcb     = ws + 33846656;        //      5,400 f
  float* drugf   = ws + 33852056;        //      9,216 f
  float* cellcat = ws + 33861272;        //      2,304 f
  float* bsums   = ws + 33863576;        //         16 f

  float* out = (float*)d_out;

  // image branch
  conv_pool_kernel<<<4096, 256, 0, stream>>>(pic, conv_w, conv_b, pooled);
  {
    dim3 g(1, 512);  // N=1024 -> 256 float4 cols; 512 splits of chunk 1024
    gemm32v_kernel<<<g, 256, 0, stream>>>(pooled, fc1_w, partial, 524288, 1024, 1024);
    reduce_kernel<<<128, 256, 0, stream>>>(partial, fc1_b, fcact, 1024, 512, 1);
  }
  // omics branches
  {
    dim3 g(4, 125);  // N=4000 -> 1000 float4 cols; 125 splits of chunk 128
    gemm32v_kernel<<<g, 256, 0, stream>>>(rna, m1w1, partial, 16000, 4000, 128);
    reduce_kernel<<<500, 256, 0, stream>>>(partial, m1b1, h1, 4000, 125, 1);
  }
  {
    dim3 g(4, 125);
    gemm32v_kernel<<<g, 256, 0, stream>>>(cnv, m2w1, partial, 16000, 4000, 128);
    reduce_kernel<<<500, 256, 0, stream>>>(partial, m2b1, h2, 4000, 125, 1);
  }
  lin36_kernel<true><<<32, 256, 0, stream>>>(h1, m1w2, m1b2, rna1, 4000);
  lin36_kernel<true><<<32, 256, 0, stream>>>(h2, m2w2, m2b2, cnv1, 4000);
  lin36_kernel<false><<<32, 256, 0, stream>>>(fcact, fc2_w, fc2_b, pic1r, 1024);

  // drug GCN
  wc_kernel<<<22, 256, 0, stream>>>(gw, gw2, wcb);
  gcn_kernel<<<128, 256, 0, stream>>>(drug_fea, drug_adj, wcb, drugf);

  // attention + CLIP loss (writes out[1], cellcat)
  head_kernel<<<1, 256, 0, stream>>>(rna1, cnv1, pic1r, aw1, ab1, aw2,
                                     logit_scale, cellcat, out);

  // pair prediction head
  pair_kernel<<<16, 256, 0, stream>>>(cellcat, drugf, index_list, target,
                                      ew1, eb1, ew2, eb2,
                                      out + 2, out + 2 + 8192, bsums);
  final_kernel<<<1, 64, 0, stream>>>(bsums, out);
}

// Round 4
// 1666.958 us; speedup vs baseline: 1.5582x; 1.5422x over previous
//
#include <hip/hip_runtime.h>
#include <hip/hip_bf16.h>
#include <math.h>

__device__ __forceinline__ void fma4(float4& a, float s, const float4& v) {
  a.x += s * v.x; a.y += s * v.y; a.z += s * v.z; a.w += s * v.w;
}

// ---------------- conv(3->32,k5,p2) + relu + maxpool2 fused ----------------
__global__ __launch_bounds__(256) void conv_pool_kernel(
    const float* __restrict__ pic, const float* __restrict__ cw,
    const float* __restrict__ cb, float* __restrict__ pooled) {
  __shared__ float ws[1200];          // 16 oc * 3 ic * 25
  __shared__ float tile[3][8][260];   // zero-padded input rows
  int bid = blockIdx.x;
  int php = bid & 63, ocg2 = (bid >> 6) & 1, b = bid >> 7;
  int tid = threadIdx.x;
  int pw = tid & 127, phl = tid >> 7;
  int ph = php * 2 + phl;
  for (int i = tid; i < 1200; i += 256) ws[i] = cw[ocg2 * 1200 + i];
  int h_base = php * 4 - 2;
  for (int i = tid; i < 3 * 8 * 260; i += 256) {
    int c = i % 260; int rr = (i / 260) & 7; int ic = i / (260 * 8);
    int h = h_base + rr, w = c - 2;
    float v = 0.f;
    if (h >= 0 && h < 256 && w >= 0 && w < 256)
      v = pic[((size_t)b * 3 + ic) * 65536 + h * 256 + w];
    tile[ic][rr][c] = v;
  }
  __syncthreads();
  float acc[16][4];
#pragma unroll
  for (int o = 0; o < 16; ++o)
#pragma unroll
    for (int q = 0; q < 4; ++q) acc[o][q] = 0.f;
  int r0 = phl * 2;
  int c0 = pw * 2;
#pragma unroll
  for (int ic = 0; ic < 3; ++ic) {
    float win[6][6];
#pragma unroll
    for (int r = 0; r < 6; ++r)
#pragma unroll
      for (int cc = 0; cc < 6; ++cc) win[r][cc] = tile[ic][r0 + r][c0 + cc];
#pragma unroll
    for (int o = 0; o < 16; ++o) {
      const float* wk = &ws[(o * 3 + ic) * 25];
#pragma unroll
      for (int kh = 0; kh < 5; ++kh)
#pragma unroll
        for (int kw = 0; kw < 5; ++kw) {
          float wv = wk[kh * 5 + kw];
          acc[o][0] += win[kh][kw] * wv;
          acc[o][1] += win[kh][kw + 1] * wv;
          acc[o][2] += win[kh + 1][kw] * wv;
          acc[o][3] += win[kh + 1][kw + 1] * wv;
        }
    }
  }
#pragma unroll
  for (int o = 0; o < 16; ++o) {
    float m = fmaxf(fmaxf(acc[o][0], acc[o][1]), fmaxf(acc[o][2], acc[o][3]));
    m = fmaxf(m + cb[ocg2 * 16 + o], 0.f);
    pooled[(((size_t)b * 32 + ocg2 * 16 + o) * 128 + ph) * 128 + pw] = m;
  }
}

// ------- split-K GEMM: X[32,K] @ W[K,N] -> partial[split][32][N] -----------
// Software-pipelined: 4-deep register double buffer on W float4 loads so the
// wave always has >=4 KB outstanding while FMAs run. Requires chunk%128==0,
// K%chunk==0, N%4==0 (true for all call sites).
__device__ __forceinline__ void gemm32p_body(
    const float* __restrict__ X, const float* __restrict__ W,
    float* __restrict__ partial, int K, int N, int chunk,
    int bx, int split, float xs[128][36]) {
  int tid = threadIdx.x;
  int colv = bx * 256 + tid;
  int col0 = colv * 4;
  bool active = col0 < N;
  int k0 = split * chunk, k1 = min(k0 + chunk, K);
  size_t Nv = (size_t)(N >> 2);
  const float4* Wv = (const float4*)W;
  float4 acc[32];
#pragma unroll
  for (int b = 0; b < 32; ++b) acc[b] = make_float4(0.f, 0.f, 0.f, 0.f);

  auto fmablk = [&](int kk, const float4& w4) {
    const float4* xr = (const float4*)xs[kk];
#pragma unroll
    for (int b4 = 0; b4 < 8; ++b4) {
      float4 xv = xr[b4];
      fma4(acc[b4 * 4 + 0], xv.x, w4);
      fma4(acc[b4 * 4 + 1], xv.y, w4);
      fma4(acc[b4 * 4 + 2], xv.z, w4);
      fma4(acc[b4 * 4 + 3], xv.w, w4);
    }
  };

  for (int kt = k0; kt < k1; kt += 128) {
    __syncthreads();
    for (int i = tid; i < 4096; i += 256) {
      int b = i >> 7, kk = i & 127;
      xs[kk][b] = X[(size_t)b * K + kt + kk];
    }
    __syncthreads();
    if (active) {
      const float4* wp = Wv + (size_t)kt * Nv + colv;
      float4 a0 = wp[0], a1 = wp[Nv], a2 = wp[2 * Nv], a3 = wp[3 * Nv];
#pragma unroll 1
      for (int g = 0; g < 31; ++g) {
        const float4* wn = wp + 4 * Nv;
        float4 b0 = wn[0], b1 = wn[Nv], b2 = wn[2 * Nv], b3 = wn[3 * Nv];
        int kk = g * 4;
        fmablk(kk + 0, a0);
        fmablk(kk + 1, a1);
        fmablk(kk + 2, a2);
        fmablk(kk + 3, a3);
        a0 = b0; a1 = b1; a2 = b2; a3 = b3;
        wp = wn;
      }
      fmablk(124, a0); fmablk(125, a1); fmablk(126, a2); fmablk(127, a3);
    }
  }
  if (active) {
    float* p = partial + (size_t)split * 32 * N + col0;
#pragma unroll
    for (int b = 0; b < 32; ++b) *(float4*)(p + (size_t)b * N) = acc[b];
  }
}

__global__ __launch_bounds__(256) void gemm32p_kernel(
    const float* __restrict__ X, const float* __restrict__ W,
    float* __restrict__ partial, int K, int N, int chunk) {
  __shared__ float xs[128][36];
  gemm32p_body(X, W, partial, K, N, chunk, blockIdx.x, blockIdx.y, xs);
}

// two independent GEMMs fused on blockIdx.z (rna / cnv branches)
__global__ __launch_bounds__(256) void gemm32p2_kernel(
    const float* __restrict__ X0, const float* __restrict__ W0, float* __restrict__ P0,
    const float* __restrict__ X1, const float* __restrict__ W1, float* __restrict__ P1,
    int K, int N, int chunk) {
  __shared__ float xs[128][36];
  if (blockIdx.z == 0)
    gemm32p_body(X0, W0, P0, K, N, chunk, blockIdx.x, blockIdx.y, xs);
  else
    gemm32p_body(X1, W1, P1, K, N, chunk, blockIdx.x, blockIdx.y, xs);
}

__device__ __forceinline__ void reduce_body(
    const float* __restrict__ partial, const float* __restrict__ bias,
    float* __restrict__ out, int N, int nsplit, int relu, int bx) {
  int i = bx * 256 + threadIdx.x;
  if (i >= 32 * N) return;
  int b = i / N, col = i - b * N;
  float s = bias[col];
  for (int sp = 0; sp < nsplit; ++sp) s += partial[((size_t)sp * 32 + b) * N + col];
  out[i] = relu ? fmaxf(s, 0.f) : s;
}

__global__ __launch_bounds__(256) void reduce_kernel(
    const float* __restrict__ partial, const float* __restrict__ bias,
    float* __restrict__ out, int N, int nsplit, int relu) {
  reduce_body(partial, bias, out, N, nsplit, relu, blockIdx.x);
}

__global__ __launch_bounds__(256) void reduce2_kernel(
    const float* __restrict__ P0, const float* __restrict__ b0, float* __restrict__ o0,
    const float* __restrict__ P1, const float* __restrict__ b1, float* __restrict__ o1,
    int N, int nsplit, int relu) {
  if (blockIdx.z == 0) reduce_body(P0, b0, o0, N, nsplit, relu, blockIdx.x);
  else                 reduce_body(P1, b1, o1, N, nsplit, relu, blockIdx.x);
}

// ---------------- x[32,K] @ W[K,36] + b (optional row softmax) --------------
template <bool SOFTMAX>
__global__ __launch_bounds__(256) void lin36_kernel(
    const float* __restrict__ X, const float* __restrict__ W,
    const float* __restrict__ bias, float* __restrict__ out, int K) {
  __shared__ float xs[4000];
  __shared__ float red[7][36];
  __shared__ float vals[36];
  __shared__ float mx, sm;
  int b = blockIdx.x, tid = threadIdx.x;
  for (int i = tid; i < K; i += 256) xs[i] = X[(size_t)b * K + i];
  __syncthreads();
  if (tid < 252) {
    int col = tid % 36, g = tid / 36;
    float s = 0.f;
    for (int k = g; k < K; k += 7) s += xs[k] * W[(size_t)k * 36 + col];
    red[g][col] = s;
  }
  __syncthreads();
  if (tid < 36) {
    float s = bias[tid];
    for (int g = 0; g < 7; ++g) s += red[g][tid];
    vals[tid] = s;
  }
  __syncthreads();
  if (SOFTMAX) {
    if (tid == 0) {
      float m = -1e30f;
      for (int j = 0; j < 36; ++j) m = fmaxf(m, vals[j]);
      float e = 0.f;
      for (int j = 0; j < 36; ++j) e += expf(vals[j] - m);
      mx = m; sm = e;
    }
    __syncthreads();
    if (tid < 36) out[b * 36 + tid] = expf(vals[tid] - mx) / sm;
  } else {
    if (tid < 36) out[b * 36 + tid] = vals[tid];
  }
}

// ---------------- Wc = gcn_w[75,288] @ gcn_w2[288,72] ----------------------
__global__ __launch_bounds__(256) void wc_kernel(
    const float* __restrict__ w1, const float* __restrict__ w2, float* __restrict__ wc) {
  int i = blockIdx.x * 256 + threadIdx.x;
  if (i >= 75 * 72) return;
  int r = i / 72, c = i - r * 72;
  float s = 0.f;
  for (int k = 0; k < 288; ++k) s += w1[r * 288 + k] * w2[k * 72 + c];
  wc[i] = s;
}

// ---------------- per-drug GCN: max(relu(Hn@(Hn@(X@Wc)))) ------------------
__global__ __launch_bounds__(256) void gcn_kernel(
    const float* __restrict__ Xg, const float* __restrict__ Ag,
    const float* __restrict__ Wc, float* __restrict__ drugfea) {
  __shared__ float Hn[64][64];
  __shared__ float Xs[64][75];
  __shared__ float Wcs[75][72];
  __shared__ float Ys[64][72];
  __shared__ float Ts[64][72];
  int d = blockIdx.x, tid = threadIdx.x;
  const float* Ad = Ag + (size_t)d * 4096;
  const float* Xd = Xg + (size_t)d * 4800;
  for (int i = tid; i < 4096; i += 256) {
    int r = i >> 6, c = i & 63;
    Hn[r][c] = (r == c) ? 1.f : Ad[c * 64 + r];
  }
  for (int i = tid; i < 4800; i += 256) Xs[i / 75][i % 75] = Xd[i];
  for (int i = tid; i < 5400; i += 256) Wcs[i / 72][i % 72] = Wc[i];
  __syncthreads();
  if (tid < 64) {
    float s = 0.f;
    for (int c = 0; c < 64; ++c) s += Hn[tid][c];
    float inv = (s == 0.f) ? 0.f : 1.f / s;
    for (int c = 0; c < 64; ++c) Hn[tid][c] *= inv;
  }
  __syncthreads();
  for (int t = tid; t < 4608; t += 256) {
    int i = t / 72, j = t - (t / 72) * 72;
    float s = 0.f;
    for (int k = 0; k < 75; ++k) s += Xs[i][k] * Wcs[k][j];
    Ys[i][j] = s;
  }
  __syncthreads();
  for (int t = tid; t < 4608; t += 256) {
    int i = t / 72, j = t - (t / 72) * 72;
    float s = 0.f;
    for (int k = 0; k < 64; ++k) s += Hn[i][k] * Ys[k][j];
    Ts[i][j] = s;
  }
  __syncthreads();
  for (int t = tid; t < 4608; t += 256) {
    int i = t / 72, j = t - (t / 72) * 72;
    float s = 0.f;
    for (int k = 0; k < 64; ++k) s += Hn[i][k] * Ts[k][j];
    Ys[i][j] = fmaxf(s, 0.f);
  }
  __syncthreads();
  if (tid < 72) {
    float m = Ys[0][tid];
    for (int i = 1; i < 64; ++i) m = fmaxf(m, Ys[i][tid]);
    drugfea[d * 72 + tid] = m;
  }
}

// ---------------- attention + CLIP loss + cell_cat (single block) ----------
__global__ __launch_bounds__(256) void head_kernel(
    const float* __restrict__ rna1, const float* __restrict__ cnv1,
    const float* __restrict__ pic1r, const float* __restrict__ aw1,
    const float* __restrict__ ab1, const float* __restrict__ aw2,
    const float* __restrict__ scale_p, float* __restrict__ cell_cat,
    float* __restrict__ dout) {
  __shared__ float z[2][32][36];
  __shared__ float pic1n[32][36];
  __shared__ float celln[32][36];
  __shared__ float fea[32][32];
  __shared__ float wvp[64];
  __shared__ float beta0, beta1;
  __shared__ float rowl[32], coll[32];
  int tid = threadIdx.x;
  for (int i = tid; i < 1152; i += 256) {
    int b = i / 36, k = i - (i / 36) * 36;
    z[0][b][k] = rna1[i];
    z[1][b][k] = cnv1[i];
    pic1n[b][k] = pic1r[i];
  }
  __syncthreads();
  {
    int p = tid >> 2, sub = tid & 3;
    int b = p >> 1, v = p & 1;
    float s = 0.f;
    for (int h = sub; h < 128; h += 4) {
      float a = ab1[h];
      for (int k = 0; k < 36; ++k) a += z[v][b][k] * aw1[k * 128 + h];
      s += tanhf(a) * aw2[h];
    }
    s += __shfl_down(s, 1, 64);
    s += __shfl_down(s, 2, 64);
    if (sub == 0) wvp[p] = s;
  }
  __syncthreads();
  if (tid == 0) {
    float w0 = 0.f, w1 = 0.f;
    for (int b = 0; b < 32; ++b) { w0 += wvp[b * 2]; w1 += wvp[b * 2 + 1]; }
    w0 /= 32.f; w1 /= 32.f;
    float m = fmaxf(w0, w1);
    float e0 = expf(w0 - m), e1 = expf(w1 - m);
    beta0 = e0 / (e0 + e1); beta1 = e1 / (e0 + e1);
  }
  __syncthreads();
  for (int i = tid; i < 1152; i += 256) {
    int b = i / 36, k = i - (i / 36) * 36;
    celln[b][k] = beta0 * z[0][b][k] + beta1 * z[1][b][k];
  }
  __syncthreads();
  if (tid < 32) {
    float s = 0.f;
    for (int k = 0; k < 36; ++k) { float x = pic1n[tid][k]; s += x * x; }
    float inv = 1.f / sqrtf(s);
    for (int k = 0; k < 36; ++k) pic1n[tid][k] *= inv;
  } else if (tid < 64) {
    int b = tid - 32;
    float s = 0.f;
    for (int k = 0; k < 36; ++k) { float x = celln[b][k]; s += x * x; }
    float inv = 1.f / sqrtf(s);
    for (int k = 0; k < 36; ++k) celln[b][k] *= inv;
  }
  __syncthreads();
  for (int i = tid; i < 1152; i += 256) {
    int b = i / 36, k = i - (i / 36) * 36;
    cell_cat[b * 72 + k] = celln[b][k];
    cell_cat[b * 72 + 36 + k] = pic1n[b][k];
  }
  float sc = *scale_p;
  for (int t = tid; t < 1024; t += 256) {
    int i = t >> 5, j = t & 31;
    float s = 0.f;
    for (int k = 0; k < 36; ++k) s += pic1n[i][k] * celln[j][k];
    fea[i][j] = sc * s;
  }
  __syncthreads();
  if (tid < 32) {
    float m = -1e30f;
    for (int j = 0; j < 32; ++j) m = fmaxf(m, fea[tid][j]);
    float e = 0.f;
    for (int j = 0; j < 32; ++j) e += expf(fea[tid][j] - m);
    rowl[tid] = (logf(e) + m) - fea[tid][tid];
  } else if (tid < 64) {
    int j = tid - 32;
    float m = -1e30f;
    for (int i = 0; i < 32; ++i) m = fmaxf(m, fea[i][j]);
    float e = 0.f;
    for (int i = 0; i < 32; ++i) e += expf(fea[i][j] - m);
    coll[j] = (logf(e) + m) - fea[j][j];
  }
  __syncthreads();
  if (tid == 0) {
    float s1 = 0.f, s2 = 0.f;
    for (int i = 0; i < 32; ++i) { s1 += rowl[i]; s2 += coll[i]; }
    dout[1] = 0.5f * (s1 / 32.f + s2 / 32.f);
  }
}

// ---------------- pair head + per-block CE partial sums --------------------
__global__ __launch_bounds__(256) void pair_kernel(
    const float* __restrict__ cell_cat, const float* __restrict__ drugfea,
    const int* __restrict__ idx, const int* __restrict__ target,
    const float* __restrict__ w1, const float* __restrict__ b1,
    const float* __restrict__ w2, const float* __restrict__ b2,
    float* __restrict__ bp_out, float* __restrict__ tgt_out,
    float* __restrict__ blocksums) {
  __shared__ float w1s[144][36];
  __shared__ float ccs[32][72];
  __shared__ float dfs[128][72];
  __shared__ float lsum[256];
  int tid = threadIdx.x;
  for (int i = tid; i < 144 * 36; i += 256) w1s[i / 36][i - (i / 36) * 36] = w1[i];
  for (int i = tid; i < 2304; i += 256) ccs[i / 72][i - (i / 72) * 72] = cell_cat[i];
  for (int i = tid; i < 9216; i += 256) dfs[i / 72][i - (i / 72) * 72] = drugfea[i];
  __syncthreads();
  int p = blockIdx.x * 256 + tid;
  int ci = idx[p * 2], dj = idx[p * 2 + 1];
  float h[36];
#pragma unroll
  for (int j = 0; j < 36; ++j) h[j] = b1[j];
  for (int k = 0; k < 72; ++k) {
    float x = ccs[ci][k];
#pragma unroll
    for (int j = 0; j < 36; ++j) h[j] += x * w1s[k][j];
  }
  for (int k = 0; k < 72; ++k) {
    float x = dfs[dj][k];
#pragma unroll
    for (int j = 0; j < 36; ++j) h[j] += x * w1s[72 + k][j];
  }
  float l0 = b2[0], l1 = b2[1];
#pragma unroll
  for (int j = 0; j < 36; ++j) {
    float hv = fmaxf(h[j], 0.f);
    l0 += hv * w2[j * 2];
    l1 += hv * w2[j * 2 + 1];
  }
  float m = fmaxf(l0, l1);
  float e0 = expf(l0 - m), e1 = expf(l1 - m);
  float inv = 1.f / (e0 + e1);
  float p0 = e0 * inv, p1 = e1 * inv;
  bp_out[p * 2] = p0;
  bp_out[p * 2 + 1] = p1;
  int t = target[p];
  float mm = fmaxf(p0, p1);
  float lse = logf(expf(p0 - mm) + expf(p1 - mm)) + mm;
  float chosen = t ? p1 : p0;
  lsum[tid] = lse - chosen;
  tgt_out[p] = (float)t;
  __syncthreads();
  for (int s = 128; s > 0; s >>= 1) {
    if (tid < s) lsum[tid] += lsum[tid + s];
    __syncthreads();
  }
  if (tid == 0) blocksums[blockIdx.x] = lsum[0];
}

__global__ void final_kernel(const float* __restrict__ blocksums, float* __restrict__ dout) {
  if (threadIdx.x == 0 && blockIdx.x == 0) {
    float s = 0.f;
    for (int i = 0; i < 16; ++i) s += blocksums[i];
    dout[0] = s / 4096.f;
  }
}

extern "C" void kernel_launch(void* const* d_in, const int* in_sizes, int n_in,
                              void* d_out, int out_size, void* d_ws, size_t ws_size,
                              hipStream_t stream) {
  (void)in_sizes; (void)n_in; (void)out_size; (void)ws_size;
  const float* pic        = (const float*)d_in[0];
  const float* rna        = (const float*)d_in[1];
  const float* cnv        = (const float*)d_in[2];
  const float* drug_fea   = (const float*)d_in[3];
  const float* drug_adj   = (const float*)d_in[4];
  const int*   index_list = (const int*)d_in[5];
  const int*   target     = (const int*)d_in[6];
  const float* logit_scale= (const float*)d_in[7];
  const float* conv_w     = (const float*)d_in[8];
  const float* conv_b     = (const float*)d_in[9];
  const float* fc1_w      = (const float*)d_in[10];
  const float* fc1_b      = (const float*)d_in[11];
  const float* fc2_w      = (const float*)d_in[12];
  const float* fc2_b      = (const float*)d_in[13];
  const float* m1w1       = (const float*)d_in[14];
  const float* m1b1       = (const float*)d_in[15];
  const float* m1w2       = (const float*)d_in[16];
  const float* m1b2       = (const float*)d_in[17];
  const float* m2w1       = (const float*)d_in[18];
  const float* m2b1       = (const float*)d_in[19];
  const float* m2w2       = (const float*)d_in[20];
  const float* m2b2       = (const float*)d_in[21];
  const float* aw1        = (const float*)d_in[22];
  const float* ab1        = (const float*)d_in[23];
  const float* aw2        = (const float*)d_in[24];
  const float* ew1        = (const float*)d_in[25];
  const float* eb1        = (const float*)d_in[26];
  const float* ew2        = (const float*)d_in[27];
  const float* eb2        = (const float*)d_in[28];
  const float* gw         = (const float*)d_in[29];
  const float* gw2        = (const float*)d_in[30];

  float* ws = (float*)d_ws;
  float* pooled  = ws;                   // 16,777,216 f
  float* pfc1    = ws + 16777216;        // 16,777,216 f (512*32*1024)
  float* pm1     = ws + 33554432;        // 16,000,000 f (125*32*4000)
  float* pm2     = ws + 49554432;        // 16,000,000 f
  float* fcact   = ws + 65554432;        //     32,768 f
  float* h1      = ws + 65587200;        //    128,000 f
  float* h2      = ws + 65715200;        //    128,000 f
  float* rna1    = ws + 65843200;        //      1,152 f
  float* cnv1    = ws + 65844352;
  float* pic1r   = ws + 65845504;
  float* wcb     = ws + 65846656;        //      5,400 f
  float* drugf   = ws + 65852056;        //      9,216 f
  float* cellcat = ws + 65861272;        //      2,304 f
  float* bsums   = ws + 65863576;        //         16 f

  float* out = (float*)d_out;

  // image branch
  conv_pool_kernel<<<4096, 256, 0, stream>>>(pic, conv_w, conv_b, pooled);
  {
    dim3 g(1, 512);  // N=1024 -> 256 float4 cols; 512 splits of chunk 1024
    gemm32p_kernel<<<g, 256, 0, stream>>>(pooled, fc1_w, pfc1, 524288, 1024, 1024);
    reduce_kernel<<<128, 256, 0, stream>>>(pfc1, fc1_b, fcact, 1024, 512, 1);
  }
  // omics branches (fused: z=0 rna, z=1 cnv)
  {
    dim3 g(4, 125, 2);  // N=4000 -> 1000 float4 cols; 125 splits of chunk 128
    gemm32p2_kernel<<<g, 256, 0, stream>>>(rna, m1w1, pm1, cnv, m2w1, pm2,
                                           16000, 4000, 128);
    dim3 r(500, 1, 2);
    reduce2_kernel<<<r, 256, 0, stream>>>(pm1, m1b1, h1, pm2, m2b1, h2, 4000, 125, 1);
  }
  lin36_kernel<true><<<32, 256, 0, stream>>>(h1, m1w2, m1b2, rna1, 4000);
  lin36_kernel<true><<<32, 256, 0, stream>>>(h2, m2w2, m2b2, cnv1, 4000);
  lin36_kernel<false><<<32, 256, 0, stream>>>(fcact, fc2_w, fc2_b, pic1r, 1024);

  // drug GCN
  wc_kernel<<<22, 256, 0, stream>>>(gw, gw2, wcb);
  gcn_kernel<<<128, 256, 0, stream>>>(drug_fea, drug_adj, wcb, drugf);

  // attention + CLIP loss (writes out[1], cellcat)
  head_kernel<<<1, 256, 0, stream>>>(rna1, cnv1, pic1r, aw1, ab1, aw2,
                                     logit_scale, cellcat, out);

  // pair prediction head
  pair_kernel<<<16, 256, 0, stream>>>(cellcat, drugf, index_list, target,
                                      ew1, eb1, ew2, eb2,
                                      out + 2, out + 2 + 8192, bsums);
  final_kernel<<<1, 64, 0, stream>>>(bsums, out);
}

// Round 5
// 1171.512 us; speedup vs baseline: 2.2172x; 1.4229x over previous
//
#include <hip/hip_runtime.h>
#include <hip/hip_bf16.h>
#include <math.h>

__device__ __forceinline__ void fma4(float4& a, float s, const float4& v) {
  a.x += s * v.x; a.y += s * v.y; a.z += s * v.z; a.w += s * v.w;
}

// ---------------- conv(3->32,k5,p2) + relu + maxpool2 fused ----------------
__global__ __launch_bounds__(256) void conv_pool_kernel(
    const float* __restrict__ pic, const float* __restrict__ cw,
    const float* __restrict__ cb, float* __restrict__ pooled) {
  __shared__ float ws[1200];          // 16 oc * 3 ic * 25
  __shared__ float tile[3][8][260];   // zero-padded input rows
  int bid = blockIdx.x;
  int php = bid & 63, ocg2 = (bid >> 6) & 1, b = bid >> 7;
  int tid = threadIdx.x;
  int pw = tid & 127, phl = tid >> 7;
  int ph = php * 2 + phl;
  for (int i = tid; i < 1200; i += 256) ws[i] = cw[ocg2 * 1200 + i];
  int h_base = php * 4 - 2;
  for (int i = tid; i < 3 * 8 * 260; i += 256) {
    int c = i % 260; int rr = (i / 260) & 7; int ic = i / (260 * 8);
    int h = h_base + rr, w = c - 2;
    float v = 0.f;
    if (h >= 0 && h < 256 && w >= 0 && w < 256)
      v = pic[((size_t)b * 3 + ic) * 65536 + h * 256 + w];
    tile[ic][rr][c] = v;
  }
  __syncthreads();
  float acc[16][4];
#pragma unroll
  for (int o = 0; o < 16; ++o)
#pragma unroll
    for (int q = 0; q < 4; ++q) acc[o][q] = 0.f;
  int r0 = phl * 2;
  int c0 = pw * 2;
#pragma unroll
  for (int ic = 0; ic < 3; ++ic) {
    float win[6][6];
#pragma unroll
    for (int r = 0; r < 6; ++r)
#pragma unroll
      for (int cc = 0; cc < 6; ++cc) win[r][cc] = tile[ic][r0 + r][c0 + cc];
#pragma unroll
    for (int o = 0; o < 16; ++o) {
      const float* wk = &ws[(o * 3 + ic) * 25];
#pragma unroll
      for (int kh = 0; kh < 5; ++kh)
#pragma unroll
        for (int kw = 0; kw < 5; ++kw) {
          float wv = wk[kh * 5 + kw];
          acc[o][0] += win[kh][kw] * wv;
          acc[o][1] += win[kh][kw + 1] * wv;
          acc[o][2] += win[kh + 1][kw] * wv;
          acc[o][3] += win[kh + 1][kw + 1] * wv;
        }
    }
  }
#pragma unroll
  for (int o = 0; o < 16; ++o) {
    float m = fmaxf(fmaxf(acc[o][0], acc[o][1]), fmaxf(acc[o][2], acc[o][3]));
    m = fmaxf(m + cb[ocg2 * 16 + o], 0.f);
    pooled[(((size_t)b * 32 + ocg2 * 16 + o) * 128 + ph) * 128 + pw] = m;
  }
}

// ------- split-K GEMM: X[32,K] @ W[K,N] -> partial[split][32][N] -----------
// 8-deep register pipeline on W float4 loads: 8 KB/lane in flight while the
// FMA block runs. chunk % 128 == 0 required.
__device__ __forceinline__ void gemm32p_body(
    const float* __restrict__ X, const float* __restrict__ W,
    float* __restrict__ partial, int K, int N, int chunk,
    int bx, int split, float xs[128][36]) {
  int tid = threadIdx.x;
  int colv = bx * 256 + tid;
  int col0 = colv * 4;
  bool active = col0 < N;
  int k0 = split * chunk, k1 = min(k0 + chunk, K);
  size_t Nv = (size_t)(N >> 2);
  const float4* Wv = (const float4*)W;
  float4 acc[32];
#pragma unroll
  for (int b = 0; b < 32; ++b) acc[b] = make_float4(0.f, 0.f, 0.f, 0.f);

  auto fmablk = [&](int kk, const float4& w4) {
    const float4* xr = (const float4*)xs[kk];
#pragma unroll
    for (int b4 = 0; b4 < 8; ++b4) {
      float4 xv = xr[b4];
      fma4(acc[b4 * 4 + 0], xv.x, w4);
      fma4(acc[b4 * 4 + 1], xv.y, w4);
      fma4(acc[b4 * 4 + 2], xv.z, w4);
      fma4(acc[b4 * 4 + 3], xv.w, w4);
    }
  };

  for (int kt = k0; kt < k1; kt += 128) {
    __syncthreads();
    for (int i = tid; i < 4096; i += 256) {
      int b = i >> 7, kk = i & 127;
      xs[kk][b] = X[(size_t)b * K + kt + kk];
    }
    __syncthreads();
    if (active) {
      const float4* wp = Wv + (size_t)kt * Nv + colv;
      float4 cur[8], nxt[8];
#pragma unroll
      for (int j = 0; j < 8; ++j) cur[j] = wp[(size_t)j * Nv];
#pragma unroll 1
      for (int g = 0; g < 15; ++g) {
        const float4* wn = wp + 8 * Nv;
#pragma unroll
        for (int j = 0; j < 8; ++j) nxt[j] = wn[(size_t)j * Nv];
        int kb = g * 8;
#pragma unroll
        for (int j = 0; j < 8; ++j) fmablk(kb + j, cur[j]);
#pragma unroll
        for (int j = 0; j < 8; ++j) cur[j] = nxt[j];
        wp = wn;
      }
#pragma unroll
      for (int j = 0; j < 8; ++j) fmablk(120 + j, cur[j]);
    }
  }
  if (active) {
    float* p = partial + (size_t)split * 32 * N + col0;
#pragma unroll
    for (int b = 0; b < 32; ++b) *(float4*)(p + (size_t)b * N) = acc[b];
  }
}

__global__ __launch_bounds__(256) void gemm32p_kernel(
    const float* __restrict__ X, const float* __restrict__ W,
    float* __restrict__ partial, int K, int N, int chunk) {
  __shared__ float xs[128][36];
  gemm32p_body(X, W, partial, K, N, chunk, blockIdx.x, blockIdx.y, xs);
}

__global__ __launch_bounds__(256) void gemm32p2_kernel(
    const float* __restrict__ X0, const float* __restrict__ W0, float* __restrict__ P0,
    const float* __restrict__ X1, const float* __restrict__ W1, float* __restrict__ P1,
    int K, int N, int chunk) {
  __shared__ float xs[128][36];
  if (blockIdx.z == 0)
    gemm32p_body(X0, W0, P0, K, N, chunk, blockIdx.x, blockIdx.y, xs);
  else
    gemm32p_body(X1, W1, P1, K, N, chunk, blockIdx.x, blockIdx.y, xs);
}

// ---- fc1 reduce, stage 1: sum 128 splits per (sy) -> p2[sy][32*N] ---------
__global__ __launch_bounds__(256) void reduce_s1_kernel(
    const float* __restrict__ partial, float* __restrict__ p2, int N) {
  int i = blockIdx.x * 256 + threadIdx.x;
  if (i >= 32 * N) return;
  int sy = blockIdx.y;
  const float* p = partial + (size_t)(sy * 128) * 32 * N + i;
  size_t st = (size_t)32 * N;
  float s0 = 0, s1 = 0, s2 = 0, s3 = 0, s4 = 0, s5 = 0, s6 = 0, s7 = 0;
  for (int sp = 0; sp < 128; sp += 8) {
    s0 += p[(sp + 0) * st]; s1 += p[(sp + 1) * st];
    s2 += p[(sp + 2) * st]; s3 += p[(sp + 3) * st];
    s4 += p[(sp + 4) * st]; s5 += p[(sp + 5) * st];
    s6 += p[(sp + 6) * st]; s7 += p[(sp + 7) * st];
  }
  p2[(size_t)sy * 32 * N + i] = ((s0 + s1) + (s2 + s3)) + ((s4 + s5) + (s6 + s7));
}

__global__ __launch_bounds__(256) void reduce_s2_kernel(
    const float* __restrict__ p2, const float* __restrict__ bias,
    float* __restrict__ out, int N, int nsy, int relu) {
  int i = blockIdx.x * 256 + threadIdx.x;
  if (i >= 32 * N) return;
  int col = i % N;
  float s = bias[col];
  for (int sy = 0; sy < nsy; ++sy) s += p2[(size_t)sy * 32 * N + i];
  out[i] = relu ? fmaxf(s, 0.f) : s;
}

// ---- generic 8-accumulator reduce (mlp branches, fused on z) --------------
__device__ __forceinline__ void reduce8_body(
    const float* __restrict__ partial, const float* __restrict__ bias,
    float* __restrict__ out, int N, int nsplit, int relu, int bx) {
  int i = bx * 256 + threadIdx.x;
  if (i >= 32 * N) return;
  int col = i % N;
  const float* p = partial + i;
  size_t st = (size_t)32 * N;
  float s0 = 0, s1 = 0, s2 = 0, s3 = 0, s4 = 0, s5 = 0, s6 = 0, s7 = 0;
  int sp = 0;
  for (; sp + 8 <= nsplit; sp += 8) {
    s0 += p[(sp + 0) * st]; s1 += p[(sp + 1) * st];
    s2 += p[(sp + 2) * st]; s3 += p[(sp + 3) * st];
    s4 += p[(sp + 4) * st]; s5 += p[(sp + 5) * st];
    s6 += p[(sp + 6) * st]; s7 += p[(sp + 7) * st];
  }
  for (; sp < nsplit; ++sp) s0 += p[(size_t)sp * st];
  float s = bias[col] + (((s0 + s1) + (s2 + s3)) + ((s4 + s5) + (s6 + s7)));
  out[i] = relu ? fmaxf(s, 0.f) : s;
}

__global__ __launch_bounds__(256) void reduce2_kernel(
    const float* __restrict__ P0, const float* __restrict__ b0, float* __restrict__ o0,
    const float* __restrict__ P1, const float* __restrict__ b1, float* __restrict__ o1,
    int N, int nsplit, int relu) {
  if (blockIdx.z == 0) reduce8_body(P0, b0, o0, N, nsplit, relu, blockIdx.x);
  else                 reduce8_body(P1, b1, o1, N, nsplit, relu, blockIdx.x);
}

// ------- x[32,K] @ W[K,36] + b, 3 branches fused, float4 W loads -----------
__global__ __launch_bounds__(256) void lin36_all_kernel(
    const float* __restrict__ X0, const float* __restrict__ W0,
    const float* __restrict__ bi0, float* __restrict__ out0,
    const float* __restrict__ X1, const float* __restrict__ W1,
    const float* __restrict__ bi1, float* __restrict__ out1,
    const float* __restrict__ X2, const float* __restrict__ W2,
    const float* __restrict__ bi2, float* __restrict__ out2) {
  const float* X; const float* W; const float* bias; float* out; int K; bool do_sm;
  if (blockIdx.y == 0)      { X = X0; W = W0; bias = bi0; out = out0; K = 4000; do_sm = true; }
  else if (blockIdx.y == 1) { X = X1; W = W1; bias = bi1; out = out1; K = 4000; do_sm = true; }
  else                      { X = X2; W = W2; bias = bi2; out = out2; K = 1024; do_sm = false; }
  __shared__ float xs[4000];
  __shared__ float red[28][36];
  __shared__ float vals[36];
  __shared__ float mxv, smv;
  int b = blockIdx.x, tid = threadIdx.x;
  for (int i = tid; i < K; i += 256) xs[i] = X[(size_t)b * K + i];
  __syncthreads();
  if (tid < 252) {
    int c4 = tid % 9, g = tid / 9;
    const float4* W4 = (const float4*)W;
    float4 s = make_float4(0.f, 0.f, 0.f, 0.f);
    for (int k = g; k < K; k += 28) fma4(s, xs[k], W4[k * 9 + c4]);
    red[g][c4 * 4 + 0] = s.x; red[g][c4 * 4 + 1] = s.y;
    red[g][c4 * 4 + 2] = s.z; red[g][c4 * 4 + 3] = s.w;
  }
  __syncthreads();
  if (tid < 36) {
    float s = bias[tid];
    for (int g = 0; g < 28; ++g) s += red[g][tid];
    vals[tid] = s;
  }
  __syncthreads();
  if (do_sm) {
    if (tid == 0) {
      float m = -1e30f;
      for (int j = 0; j < 36; ++j) m = fmaxf(m, vals[j]);
      float e = 0.f;
      for (int j = 0; j < 36; ++j) e += expf(vals[j] - m);
      mxv = m; smv = e;
    }
    __syncthreads();
    if (tid < 36) out[b * 36 + tid] = expf(vals[tid] - mxv) / smv;
  } else {
    if (tid < 36) out[b * 36 + tid] = vals[tid];
  }
}

// ---------------- Wc = gcn_w[75,288] @ gcn_w2[288,72] ----------------------
__global__ __launch_bounds__(256) void wc_kernel(
    const float* __restrict__ w1, const float* __restrict__ w2, float* __restrict__ wc) {
  int i = blockIdx.x * 256 + threadIdx.x;
  if (i >= 75 * 72) return;
  int r = i / 72, c = i - r * 72;
  float s = 0.f;
  for (int k = 0; k < 288; ++k) s += w1[r * 288 + k] * w2[k * 72 + c];
  wc[i] = s;
}

// ------- per-drug GCN: max(relu(Hn@(Hn@(X@Wc)))), 2x9 register blocking ----
__global__ __launch_bounds__(256) void gcn_kernel(
    const float* __restrict__ Xg, const float* __restrict__ Ag,
    const float* __restrict__ Wc, float* __restrict__ drugfea) {
  __shared__ float Hn[64][65];   // padded: breaks 8-way bank aliasing
  __shared__ float Xs[64][75];
  __shared__ float Wcs[75][72];
  __shared__ float Ys[64][72];
  __shared__ float Ts[64][72];
  int d = blockIdx.x, tid = threadIdx.x;
  const float* Ad = Ag + (size_t)d * 4096;
  const float* Xd = Xg + (size_t)d * 4800;
  for (int i = tid; i < 4096; i += 256) {
    int r = i & 63, c = i >> 6;              // r fast -> coalesced A^T read
    Hn[r][c] = (r == c) ? 1.f : Ad[c * 64 + r];
  }
  for (int i = tid; i < 4800; i += 256) Xs[i / 75][i % 75] = Xd[i];
  for (int i = tid; i < 5400; i += 256) Wcs[i / 72][i % 72] = Wc[i];
  __syncthreads();
  if (tid < 64) {
    float s = 0.f;
    for (int c = 0; c < 64; ++c) s += Hn[tid][c];
    float inv = (s == 0.f) ? 0.f : 1.f / s;
    for (int c = 0; c < 64; ++c) Hn[tid][c] *= inv;
  }
  __syncthreads();
  int rb = tid >> 3, cb = tid & 7;
  int r0 = rb * 2, c0 = cb * 9;
  {
    float o0[9], o1[9];
#pragma unroll
    for (int j = 0; j < 9; ++j) { o0[j] = 0.f; o1[j] = 0.f; }
    for (int k = 0; k < 75; ++k) {
      float x0 = Xs[r0][k], x1 = Xs[r0 + 1][k];
#pragma unroll
      for (int j = 0; j < 9; ++j) {
        float w = Wcs[k][c0 + j];
        o0[j] += x0 * w; o1[j] += x1 * w;
      }
    }
#pragma unroll
    for (int j = 0; j < 9; ++j) { Ys[r0][c0 + j] = o0[j]; Ys[r0 + 1][c0 + j] = o1[j]; }
  }
  __syncthreads();
  {
    float o0[9], o1[9];
#pragma unroll
    for (int j = 0; j < 9; ++j) { o0[j] = 0.f; o1[j] = 0.f; }
    for (int k = 0; k < 64; ++k) {
      float x0 = Hn[r0][k], x1 = Hn[r0 + 1][k];
#pragma unroll
      for (int j = 0; j < 9; ++j) {
        float w = Ys[k][c0 + j];
        o0[j] += x0 * w; o1[j] += x1 * w;
      }
    }
#pragma unroll
    for (int j = 0; j < 9; ++j) { Ts[r0][c0 + j] = o0[j]; Ts[r0 + 1][c0 + j] = o1[j]; }
  }
  __syncthreads();
  {
    float o0[9], o1[9];
#pragma unroll
    for (int j = 0; j < 9; ++j) { o0[j] = 0.f; o1[j] = 0.f; }
    for (int k = 0; k < 64; ++k) {
      float x0 = Hn[r0][k], x1 = Hn[r0 + 1][k];
#pragma unroll
      for (int j = 0; j < 9; ++j) {
        float w = Ts[k][c0 + j];
        o0[j] += x0 * w; o1[j] += x1 * w;
      }
    }
#pragma unroll
    for (int j = 0; j < 9; ++j) {
      Ys[r0][c0 + j] = fmaxf(o0[j], 0.f);
      Ys[r0 + 1][c0 + j] = fmaxf(o1[j], 0.f);
    }
  }
  __syncthreads();
  if (tid < 72) {
    float m = Ys[0][tid];
    for (int i = 1; i < 64; ++i) m = fmaxf(m, Ys[i][tid]);
    drugfea[d * 72 + tid] = m;
  }
}

// ---------------- attention + CLIP loss + cell_cat (single block) ----------
__global__ __launch_bounds__(256) void head_kernel(
    const float* __restrict__ rna1, const float* __restrict__ cnv1,
    const float* __restrict__ pic1r, const float* __restrict__ aw1,
    const float* __restrict__ ab1, const float* __restrict__ aw2,
    const float* __restrict__ scale_p, float* __restrict__ cell_cat,
    float* __restrict__ dout) {
  __shared__ float z[2][32][36];
  __shared__ float pic1n[32][36];
  __shared__ float celln[32][36];
  __shared__ float fea[32][32];
  __shared__ float wvp[64];
  __shared__ float beta0, beta1;
  __shared__ float rowl[32], coll[32];
  int tid = threadIdx.x;
  for (int i = tid; i < 1152; i += 256) {
    int b = i / 36, k = i - (i / 36) * 36;
    z[0][b][k] = rna1[i];
    z[1][b][k] = cnv1[i];
    pic1n[b][k] = pic1r[i];
  }
  __syncthreads();
  {
    int p = tid >> 2, sub = tid & 3;
    int b = p >> 1, v = p & 1;
    float s = 0.f;
    for (int h = sub; h < 128; h += 4) {
      float a = ab1[h];
      for (int k = 0; k < 36; ++k) a += z[v][b][k] * aw1[k * 128 + h];
      s += tanhf(a) * aw2[h];
    }
    s += __shfl_down(s, 1, 64);
    s += __shfl_down(s, 2, 64);
    if (sub == 0) wvp[p] = s;
  }
  __syncthreads();
  if (tid == 0) {
    float w0 = 0.f, w1 = 0.f;
    for (int b = 0; b < 32; ++b) { w0 += wvp[b * 2]; w1 += wvp[b * 2 + 1]; }
    w0 /= 32.f; w1 /= 32.f;
    float m = fmaxf(w0, w1);
    float e0 = expf(w0 - m), e1 = expf(w1 - m);
    beta0 = e0 / (e0 + e1); beta1 = e1 / (e0 + e1);
  }
  __syncthreads();
  for (int i = tid; i < 1152; i += 256) {
    int b = i / 36, k = i - (i / 36) * 36;
    celln[b][k] = beta0 * z[0][b][k] + beta1 * z[1][b][k];
  }
  __syncthreads();
  if (tid < 32) {
    float s = 0.f;
    for (int k = 0; k < 36; ++k) { float x = pic1n[tid][k]; s += x * x; }
    float inv = 1.f / sqrtf(s);
    for (int k = 0; k < 36; ++k) pic1n[tid][k] *= inv;
  } else if (tid < 64) {
    int b = tid - 32;
    float s = 0.f;
    for (int k = 0; k < 36; ++k) { float x = celln[b][k]; s += x * x; }
    float inv = 1.f / sqrtf(s);
    for (int k = 0; k < 36; ++k) celln[b][k] *= inv;
  }
  __syncthreads();
  for (int i = tid; i < 1152; i += 256) {
    int b = i / 36, k = i - (i / 36) * 36;
    cell_cat[b * 72 + k] = celln[b][k];
    cell_cat[b * 72 + 36 + k] = pic1n[b][k];
  }
  float sc = *scale_p;
  for (int t = tid; t < 1024; t += 256) {
    int i = t >> 5, j = t & 31;
    float s = 0.f;
    for (int k = 0; k < 36; ++k) s += pic1n[i][k] * celln[j][k];
    fea[i][j] = sc * s;
  }
  __syncthreads();
  if (tid < 32) {
    float m = -1e30f;
    for (int j = 0; j < 32; ++j) m = fmaxf(m, fea[tid][j]);
    float e = 0.f;
    for (int j = 0; j < 32; ++j) e += expf(fea[tid][j] - m);
    rowl[tid] = (logf(e) + m) - fea[tid][tid];
  } else if (tid < 64) {
    int j = tid - 32;
    float m = -1e30f;
    for (int i = 0; i < 32; ++i) m = fmaxf(m, fea[i][j]);
    float e = 0.f;
    for (int i = 0; i < 32; ++i) e += expf(fea[i][j] - m);
    coll[j] = (logf(e) + m) - fea[j][j];
  }
  __syncthreads();
  if (tid == 0) {
    float s1 = 0.f, s2 = 0.f;
    for (int i = 0; i < 32; ++i) { s1 += rowl[i]; s2 += coll[i]; }
    dout[1] = 0.5f * (s1 / 32.f + s2 / 32.f);
  }
}

// ---------------- pair head + per-block CE partial sums --------------------
__global__ __launch_bounds__(256) void pair_kernel(
    const float* __restrict__ cell_cat, const float* __restrict__ drugfea,
    const int* __restrict__ idx, const int* __restrict__ target,
    const float* __restrict__ w1, const float* __restrict__ b1,
    const float* __restrict__ w2, const float* __restrict__ b2,
    float* __restrict__ bp_out, float* __restrict__ tgt_out,
    float* __restrict__ blocksums) {
  __shared__ float w1s[144][36];   // rows are 144 B -> float4-readable
  __shared__ float ccs[32][73];    // padded: spreads gather banks
  __shared__ float dfs[128][73];
  __shared__ float w2s[72], b2s[2];
  __shared__ float lsum[256];
  int tid = threadIdx.x;
  {
    float4* dst = (float4*)&w1s[0][0];
    const float4* src = (const float4*)w1;
    for (int i = tid; i < 1296; i += 256) dst[i] = src[i];
  }
  for (int i = tid; i < 2304; i += 256) ccs[i / 72][i % 72] = cell_cat[i];
  for (int i = tid; i < 9216; i += 256) dfs[i / 72][i % 72] = drugfea[i];
  if (tid < 72) w2s[tid] = w2[tid];
  if (tid < 2) b2s[tid] = b2[tid];
  __syncthreads();
  int p = blockIdx.x * 256 + tid;
  int ci = idx[p * 2], dj = idx[p * 2 + 1];
  float4 h4[9];
  {
    const float4* bb = (const float4*)b1;
#pragma unroll
    for (int q = 0; q < 9; ++q) h4[q] = bb[q];
  }
  for (int k = 0; k < 72; ++k) {
    float x = ccs[ci][k];
    const float4* wr = (const float4*)&w1s[k][0];
#pragma unroll
    for (int q = 0; q < 9; ++q) fma4(h4[q], x, wr[q]);
  }
  for (int k = 0; k < 72; ++k) {
    float x = dfs[dj][k];
    const float4* wr = (const float4*)&w1s[72 + k][0];
#pragma unroll
    for (int q = 0; q < 9; ++q) fma4(h4[q], x, wr[q]);
  }
  float l0 = b2s[0], l1 = b2s[1];
#pragma unroll
  for (int q = 0; q < 9; ++q) {
    float hv;
    hv = fmaxf(h4[q].x, 0.f); l0 += hv * w2s[(q * 4 + 0) * 2]; l1 += hv * w2s[(q * 4 + 0) * 2 + 1];
    hv = fmaxf(h4[q].y, 0.f); l0 += hv * w2s[(q * 4 + 1) * 2]; l1 += hv * w2s[(q * 4 + 1) * 2 + 1];
    hv = fmaxf(h4[q].z, 0.f); l0 += hv * w2s[(q * 4 + 2) * 2]; l1 += hv * w2s[(q * 4 + 2) * 2 + 1];
    hv = fmaxf(h4[q].w, 0.f); l0 += hv * w2s[(q * 4 + 3) * 2]; l1 += hv * w2s[(q * 4 + 3) * 2 + 1];
  }
  float m = fmaxf(l0, l1);
  float e0 = expf(l0 - m), e1 = expf(l1 - m);
  float inv = 1.f / (e0 + e1);
  float p0 = e0 * inv, p1 = e1 * inv;
  bp_out[p * 2] = p0;
  bp_out[p * 2 + 1] = p1;
  int t = target[p];
  float mm = fmaxf(p0, p1);
  float lse = logf(expf(p0 - mm) + expf(p1 - mm)) + mm;
  float chosen = t ? p1 : p0;
  lsum[tid] = lse - chosen;
  tgt_out[p] = (float)t;
  __syncthreads();
  for (int s = 128; s > 0; s >>= 1) {
    if (tid < s) lsum[tid] += lsum[tid + s];
    __syncthreads();
  }
  if (tid == 0) blocksums[blockIdx.x] = lsum[0];
}

__global__ void final_kernel(const float* __restrict__ blocksums, float* __restrict__ dout) {
  if (threadIdx.x == 0 && blockIdx.x == 0) {
    float s = 0.f;
    for (int i = 0; i < 16; ++i) s += blocksums[i];
    dout[0] = s / 4096.f;
  }
}

extern "C" void kernel_launch(void* const* d_in, const int* in_sizes, int n_in,
                              void* d_out, int out_size, void* d_ws, size_t ws_size,
                              hipStream_t stream) {
  (void)in_sizes; (void)n_in; (void)out_size; (void)ws_size;
  const float* pic        = (const float*)d_in[0];
  const float* rna        = (const float*)d_in[1];
  const float* cnv        = (const float*)d_in[2];
  const float* drug_fea   = (const float*)d_in[3];
  const float* drug_adj   = (const float*)d_in[4];
  const int*   index_list = (const int*)d_in[5];
  const int*   target     = (const int*)d_in[6];
  const float* logit_scale= (const float*)d_in[7];
  const float* conv_w     = (const float*)d_in[8];
  const float* conv_b     = (const float*)d_in[9];
  const float* fc1_w      = (const float*)d_in[10];
  const float* fc1_b      = (const float*)d_in[11];
  const float* fc2_w      = (const float*)d_in[12];
  const float* fc2_b      = (const float*)d_in[13];
  const float* m1w1       = (const float*)d_in[14];
  const float* m1b1       = (const float*)d_in[15];
  const float* m1w2       = (const float*)d_in[16];
  const float* m1b2       = (const float*)d_in[17];
  const float* m2w1       = (const float*)d_in[18];
  const float* m2b1       = (const float*)d_in[19];
  const float* m2w2       = (const float*)d_in[20];
  const float* m2b2       = (const float*)d_in[21];
  const float* aw1        = (const float*)d_in[22];
  const float* ab1        = (const float*)d_in[23];
  const float* aw2        = (const float*)d_in[24];
  const float* ew1        = (const float*)d_in[25];
  const float* eb1        = (const float*)d_in[26];
  const float* ew2        = (const float*)d_in[27];
  const float* eb2        = (const float*)d_in[28];
  const float* gw         = (const float*)d_in[29];
  const float* gw2        = (const float*)d_in[30];

  float* ws = (float*)d_ws;
  float* pooled  = ws;                   // 16,777,216 f
  float* pfc1    = ws + 16777216;        // 33,554,432 f (1024*32*1024)
  float* p2fc1   = ws + 50331648;        //    262,144 f (8*32*1024)
  float* pm1     = ws + 50593792;        // 16,000,000 f (125*32*4000)
  float* pm2     = ws + 66593792;        // 16,000,000 f
  float* fcact   = ws + 82593792;        //     32,768 f
  float* h1      = ws + 82626560;        //    128,000 f
  float* h2      = ws + 82754560;        //    128,000 f
  float* rna1    = ws + 82882560;        //      1,152 f
  float* cnv1    = ws + 82883712;
  float* pic1r   = ws + 82884864;
  float* wcb     = ws + 82886016;        //      5,400 f
  float* drugf   = ws + 82891416;        //      9,216 f
  float* cellcat = ws + 82900632;        //      2,304 f
  float* bsums   = ws + 82902936;        //         16 f

  float* out = (float*)d_out;

  // image branch
  conv_pool_kernel<<<4096, 256, 0, stream>>>(pic, conv_w, conv_b, pooled);
  {
    dim3 g(1, 1024);  // 1024 splits of chunk 512
    gemm32p_kernel<<<g, 256, 0, stream>>>(pooled, fc1_w, pfc1, 524288, 1024, 512);
    dim3 r1(128, 8);
    reduce_s1_kernel<<<r1, 256, 0, stream>>>(pfc1, p2fc1, 1024);
    reduce_s2_kernel<<<128, 256, 0, stream>>>(p2fc1, fc1_b, fcact, 1024, 8, 1);
  }
  // omics branches (fused: z=0 rna, z=1 cnv)
  {
    dim3 g(4, 125, 2);
    gemm32p2_kernel<<<g, 256, 0, stream>>>(rna, m1w1, pm1, cnv, m2w1, pm2,
                                           16000, 4000, 128);
    dim3 r(500, 1, 2);
    reduce2_kernel<<<r, 256, 0, stream>>>(pm1, m1b1, h1, pm2, m2b1, h2, 4000, 125, 1);
  }
  {
    dim3 g(32, 3);
    lin36_all_kernel<<<g, 256, 0, stream>>>(h1, m1w2, m1b2, rna1,
                                            h2, m2w2, m2b2, cnv1,
                                            fcact, fc2_w, fc2_b, pic1r);
  }

  // drug GCN
  wc_kernel<<<22, 256, 0, stream>>>(gw, gw2, wcb);
  gcn_kernel<<<128, 256, 0, stream>>>(drug_fea, drug_adj, wcb, drugf);

  // attention + CLIP loss (writes out[1], cellcat)
  head_kernel<<<1, 256, 0, stream>>>(rna1, cnv1, pic1r, aw1, ab1, aw2,
                                     logit_scale, cellcat, out);

  // pair prediction head
  pair_kernel<<<16, 256, 0, stream>>>(cellcat, drugf, index_list, target,
                                      ew1, eb1, ew2, eb2,
                                      out + 2, out + 2 + 8192, bsums);
  final_kernel<<<1, 64, 0, stream>>>(bsums, out);
}

// Round 6
// 1135.268 us; speedup vs baseline: 2.2879x; 1.0319x over previous
//
#include <hip/hip_runtime.h>
#include <hip/hip_bf16.h>
#include <math.h>

__device__ __forceinline__ void fma4(float4& a, float s, const float4& v) {
  a.x += s * v.x; a.y += s * v.y; a.z += s * v.z; a.w += s * v.w;
}

// ---------------- conv(3->32,k5,p2) + relu + maxpool2 fused ----------------
// Weights read straight from global with wave-uniform indices -> scalar loads
// (s_load, scalar cache). LDS holds only the input tile.
__global__ __launch_bounds__(256) void conv_pool_kernel(
    const float* __restrict__ pic, const float* __restrict__ cw,
    const float* __restrict__ cb, float* __restrict__ pooled) {
  __shared__ float tile[3][8][260];   // zero-padded input rows
  int bid = blockIdx.x;
  int php = bid & 63, ocg2 = (bid >> 6) & 1, b = bid >> 7;
  int tid = threadIdx.x;
  int pw = tid & 127, phl = tid >> 7;
  int ph = php * 2 + phl;
  int h_base = php * 4 - 2;
  for (int i = tid; i < 3 * 8 * 260; i += 256) {
    int c = i % 260; int rr = (i / 260) & 7; int ic = i / (260 * 8);
    int h = h_base + rr, w = c - 2;
    float v = 0.f;
    if (h >= 0 && h < 256 && w >= 0 && w < 256)
      v = pic[((size_t)b * 3 + ic) * 65536 + h * 256 + w];
    tile[ic][rr][c] = v;
  }
  __syncthreads();
  float acc[16][4];
#pragma unroll
  for (int o = 0; o < 16; ++o)
#pragma unroll
    for (int q = 0; q < 4; ++q) acc[o][q] = 0.f;
  int r0 = phl * 2;
  int c0 = pw * 2;
#pragma unroll
  for (int ic = 0; ic < 3; ++ic) {
    float win[6][6];
#pragma unroll
    for (int r = 0; r < 6; ++r)
#pragma unroll
      for (int cc = 0; cc < 6; ++cc) win[r][cc] = tile[ic][r0 + r][c0 + cc];
#pragma unroll
    for (int o = 0; o < 16; ++o) {
      const float* __restrict__ wk = cw + ((ocg2 * 16 + o) * 3 + ic) * 25;
#pragma unroll
      for (int kh = 0; kh < 5; ++kh)
#pragma unroll
        for (int kw = 0; kw < 5; ++kw) {
          float wv = wk[kh * 5 + kw];   // uniform -> s_load
          acc[o][0] += win[kh][kw] * wv;
          acc[o][1] += win[kh][kw + 1] * wv;
          acc[o][2] += win[kh + 1][kw] * wv;
          acc[o][3] += win[kh + 1][kw + 1] * wv;
        }
    }
  }
#pragma unroll
  for (int o = 0; o < 16; ++o) {
    float m = fmaxf(fmaxf(acc[o][0], acc[o][1]), fmaxf(acc[o][2], acc[o][3]));
    m = fmaxf(m + cb[ocg2 * 16 + o], 0.f);
    pooled[(((size_t)b * 32 + ocg2 * 16 + o) * 128 + ph) * 128 + pw] = m;
  }
}

// ------- split-K GEMM: X[32,K] @ W[K,N] -> partial[split][32][N] -----------
// 8-deep register pipeline on W float4 loads. chunk and (k1-k0) % 128 == 0.
__device__ __forceinline__ void gemm32p_body(
    const float* __restrict__ X, const float* __restrict__ W,
    float* __restrict__ partial, int K, int N, int chunk,
    int bx, int split, float xs[128][36]) {
  int tid = threadIdx.x;
  int colv = bx * 256 + tid;
  int col0 = colv * 4;
  bool active = col0 < N;
  int k0 = split * chunk, k1 = min(k0 + chunk, K);
  size_t Nv = (size_t)(N >> 2);
  const float4* Wv = (const float4*)W;
  float4 acc[32];
#pragma unroll
  for (int b = 0; b < 32; ++b) acc[b] = make_float4(0.f, 0.f, 0.f, 0.f);

  auto fmablk = [&](int kk, const float4& w4) {
    const float4* xr = (const float4*)xs[kk];
#pragma unroll
    for (int b4 = 0; b4 < 8; ++b4) {
      float4 xv = xr[b4];
      fma4(acc[b4 * 4 + 0], xv.x, w4);
      fma4(acc[b4 * 4 + 1], xv.y, w4);
      fma4(acc[b4 * 4 + 2], xv.z, w4);
      fma4(acc[b4 * 4 + 3], xv.w, w4);
    }
  };

  for (int kt = k0; kt < k1; kt += 128) {
    __syncthreads();
    for (int i = tid; i < 4096; i += 256) {
      int b = i >> 7, kk = i & 127;
      xs[kk][b] = X[(size_t)b * K + kt + kk];
    }
    __syncthreads();
    if (active) {
      const float4* wp = Wv + (size_t)kt * Nv + colv;
      float4 cur[8], nxt[8];
#pragma unroll
      for (int j = 0; j < 8; ++j) cur[j] = wp[(size_t)j * Nv];
#pragma unroll 1
      for (int g = 0; g < 15; ++g) {
        const float4* wn = wp + 8 * Nv;
#pragma unroll
        for (int j = 0; j < 8; ++j) nxt[j] = wn[(size_t)j * Nv];
        int kb = g * 8;
#pragma unroll
        for (int j = 0; j < 8; ++j) fmablk(kb + j, cur[j]);
#pragma unroll
        for (int j = 0; j < 8; ++j) cur[j] = nxt[j];
        wp = wn;
      }
#pragma unroll
      for (int j = 0; j < 8; ++j) fmablk(120 + j, cur[j]);
    }
  }
  if (active) {
    float* p = partial + (size_t)split * 32 * N + col0;
#pragma unroll
    for (int b = 0; b < 32; ++b) *(float4*)(p + (size_t)b * N) = acc[b];
  }
}

__global__ __launch_bounds__(256) void gemm32p_kernel(
    const float* __restrict__ X, const float* __restrict__ W,
    float* __restrict__ partial, int K, int N, int chunk) {
  __shared__ float xs[128][36];
  gemm32p_body(X, W, partial, K, N, chunk, blockIdx.x, blockIdx.y, xs);
}

__global__ __launch_bounds__(256) void gemm32p2_kernel(
    const float* __restrict__ X0, const float* __restrict__ W0, float* __restrict__ P0,
    const float* __restrict__ X1, const float* __restrict__ W1, float* __restrict__ P1,
    int K, int N, int chunk) {
  __shared__ float xs[128][36];
  if (blockIdx.z == 0)
    gemm32p_body(X0, W0, P0, K, N, chunk, blockIdx.x, blockIdx.y, xs);
  else
    gemm32p_body(X1, W1, P1, K, N, chunk, blockIdx.x, blockIdx.y, xs);
}

// ---- fc1 reduce, stage 1: sum 128 splits per (sy) -> p2[sy][32*N] ---------
__global__ __launch_bounds__(256) void reduce_s1_kernel(
    const float* __restrict__ partial, float* __restrict__ p2, int N) {
  int i = blockIdx.x * 256 + threadIdx.x;
  if (i >= 32 * N) return;
  int sy = blockIdx.y;
  const float* p = partial + (size_t)(sy * 128) * 32 * N + i;
  size_t st = (size_t)32 * N;
  float s0 = 0, s1 = 0, s2 = 0, s3 = 0, s4 = 0, s5 = 0, s6 = 0, s7 = 0;
  for (int sp = 0; sp < 128; sp += 8) {
    s0 += p[(sp + 0) * st]; s1 += p[(sp + 1) * st];
    s2 += p[(sp + 2) * st]; s3 += p[(sp + 3) * st];
    s4 += p[(sp + 4) * st]; s5 += p[(sp + 5) * st];
    s6 += p[(sp + 6) * st]; s7 += p[(sp + 7) * st];
  }
  p2[(size_t)sy * 32 * N + i] = ((s0 + s1) + (s2 + s3)) + ((s4 + s5) + (s6 + s7));
}

__global__ __launch_bounds__(256) void reduce_s2_kernel(
    const float* __restrict__ p2, const float* __restrict__ bias,
    float* __restrict__ out, int N, int nsy, int relu) {
  int i = blockIdx.x * 256 + threadIdx.x;
  if (i >= 32 * N) return;
  int col = i % N;
  float s = bias[col];
  for (int sy = 0; sy < nsy; ++sy) s += p2[(size_t)sy * 32 * N + i];
  out[i] = relu ? fmaxf(s, 0.f) : s;
}

// ---- generic 8-accumulator reduce (mlp branches, fused on z) --------------
__device__ __forceinline__ void reduce8_body(
    const float* __restrict__ partial, const float* __restrict__ bias,
    float* __restrict__ out, int N, int nsplit, int relu, int bx) {
  int i = bx * 256 + threadIdx.x;
  if (i >= 32 * N) return;
  int col = i % N;
  const float* p = partial + i;
  size_t st = (size_t)32 * N;
  float s0 = 0, s1 = 0, s2 = 0, s3 = 0, s4 = 0, s5 = 0, s6 = 0, s7 = 0;
  int sp = 0;
  for (; sp + 8 <= nsplit; sp += 8) {
    s0 += p[(sp + 0) * st]; s1 += p[(sp + 1) * st];
    s2 += p[(sp + 2) * st]; s3 += p[(sp + 3) * st];
    s4 += p[(sp + 4) * st]; s5 += p[(sp + 5) * st];
    s6 += p[(sp + 6) * st]; s7 += p[(sp + 7) * st];
  }
  for (; sp < nsplit; ++sp) s0 += p[(size_t)sp * st];
  float s = bias[col] + (((s0 + s1) + (s2 + s3)) + ((s4 + s5) + (s6 + s7)));
  out[i] = relu ? fmaxf(s, 0.f) : s;
}

__global__ __launch_bounds__(256) void reduce2_kernel(
    const float* __restrict__ P0, const float* __restrict__ b0, float* __restrict__ o0,
    const float* __restrict__ P1, const float* __restrict__ b1, float* __restrict__ o1,
    int N, int nsplit, int relu) {
  if (blockIdx.z == 0) reduce8_body(P0, b0, o0, N, nsplit, relu, blockIdx.x);
  else                 reduce8_body(P1, b1, o1, N, nsplit, relu, blockIdx.x);
}

// ------- x[32,K] @ W[K,36] + b, 3 branches fused, float4 W loads -----------
__global__ __launch_bounds__(256) void lin36_all_kernel(
    const float* __restrict__ X0, const float* __restrict__ W0,
    const float* __restrict__ bi0, float* __restrict__ out0,
    const float* __restrict__ X1, const float* __restrict__ W1,
    const float* __restrict__ bi1, float* __restrict__ out1,
    const float* __restrict__ X2, const float* __restrict__ W2,
    const float* __restrict__ bi2, float* __restrict__ out2) {
  const float* X; const float* W; const float* bias; float* out; int K; bool do_sm;
  if (blockIdx.y == 0)      { X = X0; W = W0; bias = bi0; out = out0; K = 4000; do_sm = true; }
  else if (blockIdx.y == 1) { X = X1; W = W1; bias = bi1; out = out1; K = 4000; do_sm = true; }
  else                      { X = X2; W = W2; bias = bi2; out = out2; K = 1024; do_sm = false; }
  __shared__ float xs[4000];
  __shared__ float red[28][36];
  __shared__ float vals[36];
  __shared__ float mxv, smv;
  int b = blockIdx.x, tid = threadIdx.x;
  for (int i = tid; i < K; i += 256) xs[i] = X[(size_t)b * K + i];
  __syncthreads();
  if (tid < 252) {
    int c4 = tid % 9, g = tid / 9;
    const float4* W4 = (const float4*)W;
    float4 s = make_float4(0.f, 0.f, 0.f, 0.f);
    for (int k = g; k < K; k += 28) fma4(s, xs[k], W4[k * 9 + c4]);
    red[g][c4 * 4 + 0] = s.x; red[g][c4 * 4 + 1] = s.y;
    red[g][c4 * 4 + 2] = s.z; red[g][c4 * 4 + 3] = s.w;
  }
  __syncthreads();
  if (tid < 36) {
    float s = bias[tid];
    for (int g = 0; g < 28; ++g) s += red[g][tid];
    vals[tid] = s;
  }
  __syncthreads();
  if (do_sm) {
    if (tid == 0) {
      float m = -1e30f;
      for (int j = 0; j < 36; ++j) m = fmaxf(m, vals[j]);
      float e = 0.f;
      for (int j = 0; j < 36; ++j) e += expf(vals[j] - m);
      mxv = m; smv = e;
    }
    __syncthreads();
    if (tid < 36) out[b * 36 + tid] = expf(vals[tid] - mxv) / smv;
  } else {
    if (tid < 36) out[b * 36 + tid] = vals[tid];
  }
}

// ---------------- Wc = gcn_w[75,288] @ gcn_w2[288,72] ----------------------
__global__ __launch_bounds__(256) void wc_kernel(
    const float* __restrict__ w1, const float* __restrict__ w2, float* __restrict__ wc) {
  int i = blockIdx.x * 256 + threadIdx.x;
  if (i >= 75 * 72) return;
  int r = i / 72, c = i - r * 72;
  float s = 0.f;
  for (int k = 0; k < 288; ++k) s += w1[r * 288 + k] * w2[k * 72 + c];
  wc[i] = s;
}

// ------- per-drug GCN: max(relu(Hn@(Hn@(X@Wc)))), 2x9 register blocking ----
__global__ __launch_bounds__(256) void gcn_kernel(
    const float* __restrict__ Xg, const float* __restrict__ Ag,
    const float* __restrict__ Wc, float* __restrict__ drugfea) {
  __shared__ float Hn[64][65];
  __shared__ float Xs[64][75];
  __shared__ float Wcs[75][72];
  __shared__ float Ys[64][72];
  __shared__ float Ts[64][72];
  int d = blockIdx.x, tid = threadIdx.x;
  const float* Ad = Ag + (size_t)d * 4096;
  const float* Xd = Xg + (size_t)d * 4800;
  for (int i = tid; i < 4096; i += 256) {
    int r = i & 63, c = i >> 6;
    Hn[r][c] = (r == c) ? 1.f : Ad[c * 64 + r];
  }
  for (int i = tid; i < 4800; i += 256) Xs[i / 75][i % 75] = Xd[i];
  for (int i = tid; i < 5400; i += 256) Wcs[i / 72][i % 72] = Wc[i];
  __syncthreads();
  if (tid < 64) {
    float s = 0.f;
    for (int c = 0; c < 64; ++c) s += Hn[tid][c];
    float inv = (s == 0.f) ? 0.f : 1.f / s;
    for (int c = 0; c < 64; ++c) Hn[tid][c] *= inv;
  }
  __syncthreads();
  int rb = tid >> 3, cb = tid & 7;
  int r0 = rb * 2, c0 = cb * 9;
  {
    float o0[9], o1[9];
#pragma unroll
    for (int j = 0; j < 9; ++j) { o0[j] = 0.f; o1[j] = 0.f; }
    for (int k = 0; k < 75; ++k) {
      float x0 = Xs[r0][k], x1 = Xs[r0 + 1][k];
#pragma unroll
      for (int j = 0; j < 9; ++j) {
        float w = Wcs[k][c0 + j];
        o0[j] += x0 * w; o1[j] += x1 * w;
      }
    }
#pragma unroll
    for (int j = 0; j < 9; ++j) { Ys[r0][c0 + j] = o0[j]; Ys[r0 + 1][c0 + j] = o1[j]; }
  }
  __syncthreads();
  {
    float o0[9], o1[9];
#pragma unroll
    for (int j = 0; j < 9; ++j) { o0[j] = 0.f; o1[j] = 0.f; }
    for (int k = 0; k < 64; ++k) {
      float x0 = Hn[r0][k], x1 = Hn[r0 + 1][k];
#pragma unroll
      for (int j = 0; j < 9; ++j) {
        float w = Ys[k][c0 + j];
        o0[j] += x0 * w; o1[j] += x1 * w;
      }
    }
#pragma unroll
    for (int j = 0; j < 9; ++j) { Ts[r0][c0 + j] = o0[j]; Ts[r0 + 1][c0 + j] = o1[j]; }
  }
  __syncthreads();
  {
    float o0[9], o1[9];
#pragma unroll
    for (int j = 0; j < 9; ++j) { o0[j] = 0.f; o1[j] = 0.f; }
    for (int k = 0; k < 64; ++k) {
      float x0 = Hn[r0][k], x1 = Hn[r0 + 1][k];
#pragma unroll
      for (int j = 0; j < 9; ++j) {
        float w = Ts[k][c0 + j];
        o0[j] += x0 * w; o1[j] += x1 * w;
      }
    }
#pragma unroll
    for (int j = 0; j < 9; ++j) {
      Ys[r0][c0 + j] = fmaxf(o0[j], 0.f);
      Ys[r0 + 1][c0 + j] = fmaxf(o1[j], 0.f);
    }
  }
  __syncthreads();
  if (tid < 72) {
    float m = Ys[0][tid];
    for (int i = 1; i < 64; ++i) m = fmaxf(m, Ys[i][tid]);
    drugfea[d * 72 + tid] = m;
  }
}

// ---------------- attention + CLIP loss + cell_cat (single block) ----------
__global__ __launch_bounds__(256) void head_kernel(
    const float* __restrict__ rna1, const float* __restrict__ cnv1,
    const float* __restrict__ pic1r, const float* __restrict__ aw1,
    const float* __restrict__ ab1, const float* __restrict__ aw2,
    const float* __restrict__ scale_p, float* __restrict__ cell_cat,
    float* __restrict__ dout) {
  __shared__ float z[2][32][36];
  __shared__ float pic1n[32][36];
  __shared__ float celln[32][36];
  __shared__ float fea[32][32];
  __shared__ float wvp[64];
  __shared__ float beta0, beta1;
  __shared__ float rowl[32], coll[32];
  int tid = threadIdx.x;
  for (int i = tid; i < 1152; i += 256) {
    int b = i / 36, k = i - (i / 36) * 36;
    z[0][b][k] = rna1[i];
    z[1][b][k] = cnv1[i];
    pic1n[b][k] = pic1r[i];
  }
  __syncthreads();
  {
    int p = tid >> 2, sub = tid & 3;
    int b = p >> 1, v = p & 1;
    float s = 0.f;
    for (int h = sub; h < 128; h += 4) {
      float a = ab1[h];
      for (int k = 0; k < 36; ++k) a += z[v][b][k] * aw1[k * 128 + h];
      s += tanhf(a) * aw2[h];
    }
    s += __shfl_down(s, 1, 64);
    s += __shfl_down(s, 2, 64);
    if (sub == 0) wvp[p] = s;
  }
  __syncthreads();
  if (tid == 0) {
    float w0 = 0.f, w1 = 0.f;
    for (int b = 0; b < 32; ++b) { w0 += wvp[b * 2]; w1 += wvp[b * 2 + 1]; }
    w0 /= 32.f; w1 /= 32.f;
    float m = fmaxf(w0, w1);
    float e0 = expf(w0 - m), e1 = expf(w1 - m);
    beta0 = e0 / (e0 + e1); beta1 = e1 / (e0 + e1);
  }
  __syncthreads();
  for (int i = tid; i < 1152; i += 256) {
    int b = i / 36, k = i - (i / 36) * 36;
    celln[b][k] = beta0 * z[0][b][k] + beta1 * z[1][b][k];
  }
  __syncthreads();
  if (tid < 32) {
    float s = 0.f;
    for (int k = 0; k < 36; ++k) { float x = pic1n[tid][k]; s += x * x; }
    float inv = 1.f / sqrtf(s);
    for (int k = 0; k < 36; ++k) pic1n[tid][k] *= inv;
  } else if (tid < 64) {
    int b = tid - 32;
    float s = 0.f;
    for (int k = 0; k < 36; ++k) { float x = celln[b][k]; s += x * x; }
    float inv = 1.f / sqrtf(s);
    for (int k = 0; k < 36; ++k) celln[b][k] *= inv;
  }
  __syncthreads();
  for (int i = tid; i < 1152; i += 256) {
    int b = i / 36, k = i - (i / 36) * 36;
    cell_cat[b * 72 + k] = celln[b][k];
    cell_cat[b * 72 + 36 + k] = pic1n[b][k];
  }
  float sc = *scale_p;
  for (int t = tid; t < 1024; t += 256) {
    int i = t >> 5, j = t & 31;
    float s = 0.f;
    for (int k = 0; k < 36; ++k) s += pic1n[i][k] * celln[j][k];
    fea[i][j] = sc * s;
  }
  __syncthreads();
  if (tid < 32) {
    float m = -1e30f;
    for (int j = 0; j < 32; ++j) m = fmaxf(m, fea[tid][j]);
    float e = 0.f;
    for (int j = 0; j < 32; ++j) e += expf(fea[tid][j] - m);
    rowl[tid] = (logf(e) + m) - fea[tid][tid];
  } else if (tid < 64) {
    int j = tid - 32;
    float m = -1e30f;
    for (int i = 0; i < 32; ++i) m = fmaxf(m, fea[i][j]);
    float e = 0.f;
    for (int i = 0; i < 32; ++i) e += expf(fea[i][j] - m);
    coll[j] = (logf(e) + m) - fea[j][j];
  }
  __syncthreads();
  if (tid == 0) {
    float s1 = 0.f, s2 = 0.f;
    for (int i = 0; i < 32; ++i) { s1 += rowl[i]; s2 += coll[i]; }
    dout[1] = 0.5f * (s1 / 32.f + s2 / 32.f);
  }
}

// ---------------- pair head + per-block CE partial sums --------------------
__global__ __launch_bounds__(256) void pair_kernel(
    const float* __restrict__ cell_cat, const float* __restrict__ drugfea,
    const int* __restrict__ idx, const int* __restrict__ target,
    const float* __restrict__ w1, const float* __restrict__ b1,
    const float* __restrict__ w2, const float* __restrict__ b2,
    float* __restrict__ bp_out, float* __restrict__ tgt_out,
    float* __restrict__ blocksums) {
  __shared__ float w1s[144][36];
  __shared__ float ccs[32][73];
  __shared__ float dfs[128][73];
  __shared__ float w2s[72], b2s[2];
  __shared__ float lsum[256];
  int tid = threadIdx.x;
  {
    float4* dst = (float4*)&w1s[0][0];
    const float4* src = (const float4*)w1;
    for (int i = tid; i < 1296; i += 256) dst[i] = src[i];
  }
  for (int i = tid; i < 2304; i += 256) ccs[i / 72][i % 72] = cell_cat[i];
  for (int i = tid; i < 9216; i += 256) dfs[i / 72][i % 72] = drugfea[i];
  if (tid < 72) w2s[tid] = w2[tid];
  if (tid < 2) b2s[tid] = b2[tid];
  __syncthreads();
  int p = blockIdx.x * 256 + tid;
  int ci = idx[p * 2], dj = idx[p * 2 + 1];
  float4 h4[9];
  {
    const float4* bb = (const float4*)b1;
#pragma unroll
    for (int q = 0; q < 9; ++q) h4[q] = bb[q];
  }
  for (int k = 0; k < 72; ++k) {
    float x = ccs[ci][k];
    const float4* wr = (const float4*)&w1s[k][0];
#pragma unroll
    for (int q = 0; q < 9; ++q) fma4(h4[q], x, wr[q]);
  }
  for (int k = 0; k < 72; ++k) {
    float x = dfs[dj][k];
    const float4* wr = (const float4*)&w1s[72 + k][0];
#pragma unroll
    for (int q = 0; q < 9; ++q) fma4(h4[q], x, wr[q]);
  }
  float l0 = b2s[0], l1 = b2s[1];
#pragma unroll
  for (int q = 0; q < 9; ++q) {
    float hv;
    hv = fmaxf(h4[q].x, 0.f); l0 += hv * w2s[(q * 4 + 0) * 2]; l1 += hv * w2s[(q * 4 + 0) * 2 + 1];
    hv = fmaxf(h4[q].y, 0.f); l0 += hv * w2s[(q * 4 + 1) * 2]; l1 += hv * w2s[(q * 4 + 1) * 2 + 1];
    hv = fmaxf(h4[q].z, 0.f); l0 += hv * w2s[(q * 4 + 2) * 2]; l1 += hv * w2s[(q * 4 + 2) * 2 + 1];
    hv = fmaxf(h4[q].w, 0.f); l0 += hv * w2s[(q * 4 + 3) * 2]; l1 += hv * w2s[(q * 4 + 3) * 2 + 1];
  }
  float m = fmaxf(l0, l1);
  float e0 = expf(l0 - m), e1 = expf(l1 - m);
  float inv = 1.f / (e0 + e1);
  float p0 = e0 * inv, p1 = e1 * inv;
  bp_out[p * 2] = p0;
  bp_out[p * 2 + 1] = p1;
  int t = target[p];
  float mm = fmaxf(p0, p1);
  float lse = logf(expf(p0 - mm) + expf(p1 - mm)) + mm;
  float chosen = t ? p1 : p0;
  lsum[tid] = lse - chosen;
  tgt_out[p] = (float)t;
  __syncthreads();
  for (int s = 128; s > 0; s >>= 1) {
    if (tid < s) lsum[tid] += lsum[tid + s];
    __syncthreads();
  }
  if (tid == 0) blocksums[blockIdx.x] = lsum[0];
}

__global__ void final_kernel(const float* __restrict__ blocksums, float* __restrict__ dout) {
  if (threadIdx.x == 0 && blockIdx.x == 0) {
    float s = 0.f;
    for (int i = 0; i < 16; ++i) s += blocksums[i];
    dout[0] = s / 4096.f;
  }
}

extern "C" void kernel_launch(void* const* d_in, const int* in_sizes, int n_in,
                              void* d_out, int out_size, void* d_ws, size_t ws_size,
                              hipStream_t stream) {
  (void)in_sizes; (void)n_in; (void)out_size; (void)ws_size;
  const float* pic        = (const float*)d_in[0];
  const float* rna        = (const float*)d_in[1];
  const float* cnv        = (const float*)d_in[2];
  const float* drug_fea   = (const float*)d_in[3];
  const float* drug_adj   = (const float*)d_in[4];
  const int*   index_list = (const int*)d_in[5];
  const int*   target     = (const int*)d_in[6];
  const float* logit_scale= (const float*)d_in[7];
  const float* conv_w     = (const float*)d_in[8];
  const float* conv_b     = (const float*)d_in[9];
  const float* fc1_w      = (const float*)d_in[10];
  const float* fc1_b      = (const float*)d_in[11];
  const float* fc2_w      = (const float*)d_in[12];
  const float* fc2_b      = (const float*)d_in[13];
  const float* m1w1       = (const float*)d_in[14];
  const float* m1b1       = (const float*)d_in[15];
  const float* m1w2       = (const float*)d_in[16];
  const float* m1b2       = (const float*)d_in[17];
  const float* m2w1       = (const float*)d_in[18];
  const float* m2b1       = (const float*)d_in[19];
  const float* m2w2       = (const float*)d_in[20];
  const float* m2b2       = (const float*)d_in[21];
  const float* aw1        = (const float*)d_in[22];
  const float* ab1        = (const float*)d_in[23];
  const float* aw2        = (const float*)d_in[24];
  const float* ew1        = (const float*)d_in[25];
  const float* eb1        = (const float*)d_in[26];
  const float* ew2        = (const float*)d_in[27];
  const float* eb2        = (const float*)d_in[28];
  const float* gw         = (const float*)d_in[29];
  const float* gw2        = (const float*)d_in[30];

  float* ws = (float*)d_ws;
  float* pooled  = ws;                   // 16,777,216 f
  float* pfc1    = ws + 16777216;        // 16,777,216 f (512*32*1024)
  float* p2fc1   = ws + 33554432;        //    131,072 f (4*32*1024)
  float* pm1     = ws + 33685504;        //  8,064,000 f (63*32*4000)
  float* pm2     = ws + 41749504;        //  8,064,000 f
  float* fcact   = ws + 49813504;        //     32,768 f
  float* h1      = ws + 49846272;        //    128,000 f
  float* h2      = ws + 49974272;        //    128,000 f
  float* rna1    = ws + 50102272;        //      1,152 f
  float* cnv1    = ws + 50103424;
  float* pic1r   = ws + 50104576;
  float* wcb     = ws + 50105728;        //      5,400 f
  float* drugf   = ws + 50111128;        //      9,216 f
  float* cellcat = ws + 50120344;        //      2,304 f
  float* bsums   = ws + 50122648;        //         16 f

  float* out = (float*)d_out;

  // image branch
  conv_pool_kernel<<<4096, 256, 0, stream>>>(pic, conv_w, conv_b, pooled);
  {
    dim3 g(1, 512);  // 512 splits of chunk 1024
    gemm32p_kernel<<<g, 256, 0, stream>>>(pooled, fc1_w, pfc1, 524288, 1024, 1024);
    dim3 r1(128, 4);
    reduce_s1_kernel<<<r1, 256, 0, stream>>>(pfc1, p2fc1, 1024);
    reduce_s2_kernel<<<128, 256, 0, stream>>>(p2fc1, fc1_b, fcact, 1024, 4, 1);
  }
  // omics branches (fused: z=0 rna, z=1 cnv); 63 splits of chunk 256
  {
    dim3 g(4, 63, 2);
    gemm32p2_kernel<<<g, 256, 0, stream>>>(rna, m1w1, pm1, cnv, m2w1, pm2,
                                           16000, 4000, 256);
    dim3 r(500, 1, 2);
    reduce2_kernel<<<r, 256, 0, stream>>>(pm1, m1b1, h1, pm2, m2b1, h2, 4000, 63, 1);
  }
  {
    dim3 g(32, 3);
    lin36_all_kernel<<<g, 256, 0, stream>>>(h1, m1w2, m1b2, rna1,
                                            h2, m2w2, m2b2, cnv1,
                                            fcact, fc2_w, fc2_b, pic1r);
  }

  // drug GCN
  wc_kernel<<<22, 256, 0, stream>>>(gw, gw2, wcb);
  gcn_kernel<<<128, 256, 0, stream>>>(drug_fea, drug_adj, wcb, drugf);

  // attention + CLIP loss (writes out[1], cellcat)
  head_kernel<<<1, 256, 0, stream>>>(rna1, cnv1, pic1r, aw1, ab1, aw2,
                                     logit_scale, cellcat, out);

  // pair prediction head
  pair_kernel<<<16, 256, 0, stream>>>(cellcat, drugf, index_list, target,
                                      ew1, eb1, ew2, eb2,
                                      out + 2, out + 2 + 8192, bsums);
  final_kernel<<<1, 64, 0, stream>>>(bsums, out);
}